// Round 4
// baseline (509.600 us; speedup 1.0000x reference)
//
#include <hip/hip_runtime.h>
#include <hip/hip_bf16.h>
#include <math.h>

#define N_NODES 50000
#define N_EDGES 1600000
#define H 64
#define G_GRAPHS 512
#define C_CLS 2
#define BN_EPS 1e-5f

// ---------- CSR build: histogram of dst + per-edge rank (4 edges/thread) ----------
__global__ void hist_kernel(const int* __restrict__ dst, int* __restrict__ count,
                            int* __restrict__ rank) {
    int e4 = blockIdx.x * blockDim.x + threadIdx.x;
    if (e4 >= N_EDGES / 4) return;
    int4 d = ((const int4*)dst)[e4];
    int4 r;
    r.x = atomicAdd(&count[d.x], 1);
    r.y = atomicAdd(&count[d.y], 1);
    r.z = atomicAdd(&count[d.z], 1);
    r.w = atomicAdd(&count[d.w], 1);
    ((int4*)rank)[e4] = r;
}

// ---------- fused exclusive scan: one block, 1024 threads ----------
#define SCAN_T 1024
#define SCAN_PER ((N_NODES + SCAN_T - 1) / SCAN_T)   // 49
__global__ __launch_bounds__(1024) void scan_kernel(const int* __restrict__ count,
                                                    int* __restrict__ row_start) {
    __shared__ int s[SCAN_T];
    int t = threadIdx.x;
    int start = t * SCAN_PER;
    int sum = 0;
    for (int i = 0; i < SCAN_PER; i++) {
        int idx = start + i;
        if (idx < N_NODES) sum += count[idx];
    }
    s[t] = sum;
    __syncthreads();
    for (int off = 1; off < SCAN_T; off <<= 1) {
        int v = 0;
        if (t >= off) v = s[t - off];
        __syncthreads();
        if (t >= off) s[t] += v;
        __syncthreads();
    }
    int run = s[t] - sum;   // exclusive prefix of this thread's chunk
    for (int i = 0; i < SCAN_PER; i++) {
        int idx = start + i;
        if (idx < N_NODES) { row_start[idx] = run; run += count[idx]; }
    }
    if (t == 0) row_start[N_NODES] = N_EDGES;
}

// ---------- CSR fill (atomic-free, 4 edges/thread) ----------
__global__ void fill_kernel(const int* __restrict__ src, const int* __restrict__ dst,
                            const int* __restrict__ rank, const int* __restrict__ row_start,
                            int* __restrict__ edge_src) {
    int e4 = blockIdx.x * blockDim.x + threadIdx.x;
    if (e4 >= N_EDGES / 4) return;
    int4 s = ((const int4*)src)[e4];
    int4 d = ((const int4*)dst)[e4];
    int4 r = ((const int4*)rank)[e4];
    edge_src[row_start[d.x] + r.x] = s.x;
    edge_src[row_start[d.y] + r.y] = s.y;
    edge_src[row_start[d.z] + r.z] = s.z;
    edge_src[row_start[d.w] + r.w] = s.w;
}

// ---------- layer 1: gather(din=3) + MLP, one wave per node, bf16 out ----------
__global__ __launch_bounds__(256) void gin_layer3_kernel(
    const float* __restrict__ x, const int* __restrict__ row_start,
    const int* __restrict__ edge_src,
    const float* __restrict__ w1, const float* __restrict__ b1,
    const float* __restrict__ bn_g, const float* __restrict__ bn_b,
    const float* __restrict__ bn_m, const float* __restrict__ bn_v,
    const float* __restrict__ w2, const float* __restrict__ b2,
    __hip_bfloat16* __restrict__ hout) {
    __shared__ float s_w1[3 * H];
    __shared__ float s_w2[H * H];
    __shared__ float s_mid[4][H];
    __shared__ float s_scale[H], s_shift[H], s_b1[H], s_b2[H];

    int tid = threadIdx.x;
    for (int i = tid; i < 3 * H; i += 256) s_w1[i] = w1[i];
    for (int i = tid; i < H * H; i += 256) s_w2[i] = w2[i];
    if (tid < H) {
        float sc = rsqrtf(bn_v[tid] + BN_EPS) * bn_g[tid];
        s_scale[tid] = sc;
        s_shift[tid] = bn_b[tid] - bn_m[tid] * sc;
        s_b1[tid] = b1[tid];
        s_b2[tid] = b2[tid];
    }
    __syncthreads();

    int wave = tid >> 6;
    int j = tid & 63;
    int node = blockIdx.x * 4 + wave;

    int rs = row_start[node], re = row_start[node + 1];
    float a0 = 0.f, a1 = 0.f, a2 = 0.f;
    for (int t = rs + j; t < re; t += 64) {
        int s = edge_src[t];
        a0 += x[s * 3 + 0];
        a1 += x[s * 3 + 1];
        a2 += x[s * 3 + 2];
    }
#pragma unroll
    for (int off = 32; off > 0; off >>= 1) {
        a0 += __shfl_xor(a0, off);
        a1 += __shfl_xor(a1, off);
        a2 += __shfl_xor(a2, off);
    }
    float in0 = a0 + x[node * 3 + 0];
    float in1 = a1 + x[node * 3 + 1];
    float in2 = a2 + x[node * 3 + 2];

    float m = s_b1[j] + in0 * s_w1[0 * H + j] + in1 * s_w1[1 * H + j] + in2 * s_w1[2 * H + j];
    m = m * s_scale[j] + s_shift[j];
    m = fmaxf(m, 0.f);
    s_mid[wave][j] = m;
    __syncthreads();
    float o = s_b2[j];
#pragma unroll
    for (int k = 0; k < H; k++) o += s_mid[wave][k] * s_w2[k * H + j];
    o = fmaxf(o, 0.f);
    hout[(size_t)node * H + j] = __float2bfloat16(o);
}

// ---------- layers 2/3: packed bf16x2 gather + MLP, one wave per node ----------
// lanes 0-31 process even edges, lanes 32-63 odd edges; each lane loads a
// bf16x2 (features 2*jm, 2*jm+1). One load instruction covers TWO edges.
__global__ __launch_bounds__(512) void gin_layer64_kernel(
    const __hip_bfloat16* __restrict__ hin, const int* __restrict__ row_start,
    const int* __restrict__ edge_src,
    const float* __restrict__ w1, const float* __restrict__ b1,
    const float* __restrict__ bn_g, const float* __restrict__ bn_b,
    const float* __restrict__ bn_m, const float* __restrict__ bn_v,
    const float* __restrict__ w2, const float* __restrict__ b2,
    __hip_bfloat16* __restrict__ hout) {
    __shared__ float s_w1[H * H];
    __shared__ float s_w2[H * H];
    __shared__ float s_in[8][H];
    __shared__ float s_mid[8][H];
    __shared__ float s_scale[H], s_shift[H], s_b1[H], s_b2[H];

    int tid = threadIdx.x;
    for (int i = tid; i < H * H; i += 512) { s_w1[i] = w1[i]; s_w2[i] = w2[i]; }
    if (tid < H) {
        float sc = rsqrtf(bn_v[tid] + BN_EPS) * bn_g[tid];
        s_scale[tid] = sc;
        s_shift[tid] = bn_b[tid] - bn_m[tid] * sc;
        s_b1[tid] = b1[tid];
        s_b2[tid] = b2[tid];
    }
    __syncthreads();

    int wave = tid >> 6;
    int j = tid & 63;
    int half = j >> 5;    // 0: even edges, 1: odd edges
    int jm = j & 31;      // feature pair index
    int node = blockIdx.x * 8 + wave;

    const __hip_bfloat162* hin2 = (const __hip_bfloat162*)hin;
    int rs = row_start[node], re = row_start[node + 1];
    float ax = 0.f, ay = 0.f, bx = 0.f, by = 0.f;
    for (int base = rs; base < re; base += 64) {
        int idx = base + j;
        int sv = (idx < re) ? edge_src[idx] : 0;   // coalesced chunk of edge ids
        int cnt = min(64, re - base);
        int i = 0;
        for (; i + 3 < cnt; i += 4) {              // 4 edges per iter (2 per half)
            int s0 = __shfl(sv, i + half);
            int s1 = __shfl(sv, i + 2 + half);
            __hip_bfloat162 v0 = hin2[(size_t)s0 * 32 + jm];
            __hip_bfloat162 v1 = hin2[(size_t)s1 * 32 + jm];
            ax += __low2float(v0); ay += __high2float(v0);
            bx += __low2float(v1); by += __high2float(v1);
        }
        for (; i + 1 < cnt; i += 2) {              // leftover pair
            int s0 = __shfl(sv, i + half);
            __hip_bfloat162 v0 = hin2[(size_t)s0 * 32 + jm];
            ax += __low2float(v0); ay += __high2float(v0);
        }
        if (i < cnt) {                             // odd tail: only half 0 adds
            int s0 = __shfl(sv, i);
            __hip_bfloat162 v0 = hin2[(size_t)s0 * 32 + jm];
            float vx = __low2float(v0), vy = __high2float(v0);
            if (half == 0) { ax += vx; ay += vy; }
        }
    }
    ax += bx; ay += by;
    ax += __shfl_xor(ax, 32);
    ay += __shfl_xor(ay, 32);
    __hip_bfloat162 vself = hin2[(size_t)node * 32 + jm];
    if (half == 0) {
        s_in[wave][2 * jm]     = ax + __low2float(vself);
        s_in[wave][2 * jm + 1] = ay + __high2float(vself);
    }
    __syncthreads();

    float m = s_b1[j];
#pragma unroll
    for (int k = 0; k < H; k++) m += s_in[wave][k] * s_w1[k * H + j];
    m = m * s_scale[j] + s_shift[j];
    m = fmaxf(m, 0.f);
    s_mid[wave][j] = m;
    __syncthreads();

    float o = s_b2[j];
#pragma unroll
    for (int k = 0; k < H; k++) o += s_mid[wave][k] * s_w2[k * H + j];
    o = fmaxf(o, 0.f);
    hout[(size_t)node * H + j] = __float2bfloat16(o);
}

// ---------- pool (batch sorted -> range per graph) + head ----------
__global__ __launch_bounds__(192) void pool_head_kernel(
    const __hip_bfloat16* __restrict__ h1, const __hip_bfloat16* __restrict__ h2,
    const __hip_bfloat16* __restrict__ h3, const int* __restrict__ batch,
    const float* __restrict__ lin1_w, const float* __restrict__ lin1_b,
    const float* __restrict__ lin2_w, const float* __restrict__ lin2_b,
    float* __restrict__ out) {
    __shared__ float s_row[3 * H];
    __shared__ float s_mid[3 * H];
    __shared__ float s_z[C_CLS];
    __shared__ int s_se[2];

    int g = blockIdx.x;
    int j = threadIdx.x;
    if (j < 2) {
        int target = g + j;
        int lo = 0, hi = N_NODES;
        while (lo < hi) {
            int mid = (lo + hi) >> 1;
            if (batch[mid] < target) lo = mid + 1; else hi = mid;
        }
        s_se[j] = lo;
    }
    __syncthreads();
    int ns = s_se[0], ne = s_se[1];

    int which = j >> 6;       // 0,1,2
    int f = j & 63;
    const __hip_bfloat16* h = (which == 0) ? h1 : ((which == 1) ? h2 : h3);
    float p0 = 0.f, p1 = 0.f, p2 = 0.f, p3 = 0.f;
    int n = ns;
    for (; n + 3 < ne; n += 4) {
        p0 += __bfloat162float(h[(size_t)n * H + f]);
        p1 += __bfloat162float(h[(size_t)(n + 1) * H + f]);
        p2 += __bfloat162float(h[(size_t)(n + 2) * H + f]);
        p3 += __bfloat162float(h[(size_t)(n + 3) * H + f]);
    }
    for (; n < ne; n++) p0 += __bfloat162float(h[(size_t)n * H + f]);
    s_row[j] = (p0 + p1) + (p2 + p3);
    __syncthreads();

    float acc = lin1_b[j];
    for (int k = 0; k < 3 * H; k++) acc += s_row[k] * lin1_w[k * (3 * H) + j];
    s_mid[j] = fmaxf(acc, 0.f);
    __syncthreads();

    if (j < C_CLS) {
        float z = lin2_b[j];
        for (int k = 0; k < 3 * H; k++) z += s_mid[k] * lin2_w[k * C_CLS + j];
        s_z[j] = z;
    }
    __syncthreads();
    if (j < C_CLS) {
        float z0 = s_z[0], z1 = s_z[1];
        float mx = fmaxf(z0, z1);
        float lse = mx + logf(expf(z0 - mx) + expf(z1 - mx));
        out[g * C_CLS + j] = s_z[j];
        out[G_GRAPHS * C_CLS + g * C_CLS + j] = s_z[j] - lse;
    }
}

extern "C" void kernel_launch(void* const* d_in, const int* in_sizes, int n_in,
                              void* d_out, int out_size, void* d_ws, size_t ws_size,
                              hipStream_t stream) {
    const float* x = (const float*)d_in[0];
    const float* cw1[3], *cb1[3], *cg[3], *cbb[3], *cm[3], *cv[3], *cw2[3], *cb2[3];
    for (int l = 0; l < 3; l++) {
        int b = 1 + 8 * l;
        cw1[l] = (const float*)d_in[b + 0];
        cb1[l] = (const float*)d_in[b + 1];
        cg[l]  = (const float*)d_in[b + 2];
        cbb[l] = (const float*)d_in[b + 3];
        cm[l]  = (const float*)d_in[b + 4];
        cv[l]  = (const float*)d_in[b + 5];
        cw2[l] = (const float*)d_in[b + 6];
        cb2[l] = (const float*)d_in[b + 7];
    }
    const float* lin1_w = (const float*)d_in[25];
    const float* lin1_b = (const float*)d_in[26];
    const float* lin2_w = (const float*)d_in[27];
    const float* lin2_b = (const float*)d_in[28];
    const int* edge_index = (const int*)d_in[29];
    const int* batch = (const int*)d_in[30];
    const int* src = edge_index;
    const int* dst = edge_index + N_EDGES;
    float* out = (float*)d_out;

    // workspace layout (int-aligned; h buffers 4B-aligned for bf16x2 loads)
    int* edge_src = (int*)d_ws;                     // E
    int* rank = edge_src + N_EDGES;                 // E
    int* count = rank + N_EDGES;                    // N
    int* row_start = count + N_NODES;               // N+1
    __hip_bfloat16* h1 = (__hip_bfloat16*)(row_start + N_NODES + 2);  // N*H
    __hip_bfloat16* h2 = h1 + (size_t)N_NODES * H;
    __hip_bfloat16* h3 = h2 + (size_t)N_NODES * H;

    // ---- build CSR (dst -> list of src) ----
    hipMemsetAsync(count, 0, N_NODES * sizeof(int), stream);
    hist_kernel<<<(N_EDGES / 4 + 255) / 256, 256, 0, stream>>>(dst, count, rank);
    scan_kernel<<<1, SCAN_T, 0, stream>>>(count, row_start);
    fill_kernel<<<(N_EDGES / 4 + 255) / 256, 256, 0, stream>>>(src, dst, rank, row_start, edge_src);

    // ---- layer 1 ----
    gin_layer3_kernel<<<N_NODES / 4, 256, 0, stream>>>(x, row_start, edge_src,
        cw1[0], cb1[0], cg[0], cbb[0], cm[0], cv[0], cw2[0], cb2[0], h1);
    // ---- layer 2 ----
    gin_layer64_kernel<<<N_NODES / 8, 512, 0, stream>>>(h1, row_start, edge_src,
        cw1[1], cb1[1], cg[1], cbb[1], cm[1], cv[1], cw2[1], cb2[1], h2);
    // ---- layer 3 ----
    gin_layer64_kernel<<<N_NODES / 8, 512, 0, stream>>>(h2, row_start, edge_src,
        cw1[2], cb1[2], cg[2], cbb[2], cm[2], cv[2], cw2[2], cb2[2], h3);
    // ---- pool + head ----
    pool_head_kernel<<<G_GRAPHS, 3 * H, 0, stream>>>(h1, h2, h3, batch,
        lin1_w, lin1_b, lin2_w, lin2_b, out);
}

// Round 5
// 425.227 us; speedup vs baseline: 1.1984x; 1.1984x over previous
//
#include <hip/hip_runtime.h>
#include <hip/hip_bf16.h>
#include <math.h>

#define N_NODES 50000
#define N_EDGES 1600000
#define H 64
#define G_GRAPHS 512
#define C_CLS 2
#define BN_EPS 1e-5f

#define SCAN_CHUNK 1024            // elements per scan block (256 thr x 4)
#define SCAN_BLOCKS ((N_NODES + SCAN_CHUNK - 1) / SCAN_CHUNK)   // 49

// ---------- CSR build: histogram of dst + per-edge rank (4 edges/thread) ----------
__global__ void hist_kernel(const int* __restrict__ dst, int* __restrict__ count,
                            int* __restrict__ rank) {
    int e4 = blockIdx.x * blockDim.x + threadIdx.x;
    if (e4 >= N_EDGES / 4) return;
    int4 d = ((const int4*)dst)[e4];
    int4 r;
    r.x = atomicAdd(&count[d.x], 1);
    r.y = atomicAdd(&count[d.y], 1);
    r.z = atomicAdd(&count[d.z], 1);
    r.w = atomicAdd(&count[d.w], 1);
    ((int4*)rank)[e4] = r;
}

// ---------- scan pass 1: per-block sums ----------
__global__ __launch_bounds__(256) void scan_sums_kernel(const int* __restrict__ count,
                                                        int* __restrict__ block_sums) {
    __shared__ int s[256];
    int base = blockIdx.x * SCAN_CHUNK + threadIdx.x * 4;
    int sum = 0;
#pragma unroll
    for (int i = 0; i < 4; i++) {
        int idx = base + i;
        if (idx < N_NODES) sum += count[idx];
    }
    s[threadIdx.x] = sum;
    __syncthreads();
    for (int off = 128; off > 0; off >>= 1) {
        if (threadIdx.x < off) s[threadIdx.x] += s[threadIdx.x + off];
        __syncthreads();
    }
    if (threadIdx.x == 0) block_sums[blockIdx.x] = s[0];
}

// ---------- scan pass 2: exclusive scan of block sums (small) ----------
__global__ void scan_offsets_kernel(int* __restrict__ block_sums, int* __restrict__ row_start) {
    if (threadIdx.x == 0 && blockIdx.x == 0) {
        int acc = 0;
        for (int i = 0; i < SCAN_BLOCKS; i++) {
            int v = block_sums[i];
            block_sums[i] = acc;
            acc += v;
        }
        row_start[N_NODES] = N_EDGES;
    }
}

// ---------- scan pass 3: per-block exclusive scan ----------
__global__ __launch_bounds__(256) void scan_final_kernel(const int* __restrict__ count,
                                                         const int* __restrict__ block_sums,
                                                         int* __restrict__ row_start) {
    __shared__ int s[256];
    int base = blockIdx.x * SCAN_CHUNK + threadIdx.x * 4;
    int c[4], local[4];
    int sum = 0;
#pragma unroll
    for (int i = 0; i < 4; i++) {
        int idx = base + i;
        c[i] = (idx < N_NODES) ? count[idx] : 0;
        local[i] = sum;
        sum += c[i];
    }
    s[threadIdx.x] = sum;
    __syncthreads();
    for (int off = 1; off < 256; off <<= 1) {
        int v = 0;
        if (threadIdx.x >= off) v = s[threadIdx.x - off];
        __syncthreads();
        if (threadIdx.x >= off) s[threadIdx.x] += v;
        __syncthreads();
    }
    int tprefix = s[threadIdx.x] - sum;
    int boff = block_sums[blockIdx.x];
#pragma unroll
    for (int i = 0; i < 4; i++) {
        int idx = base + i;
        if (idx < N_NODES) row_start[idx] = boff + tprefix + local[i];
    }
}

// ---------- CSR fill (atomic-free, 4 edges/thread) ----------
__global__ void fill_kernel(const int* __restrict__ src, const int* __restrict__ dst,
                            const int* __restrict__ rank, const int* __restrict__ row_start,
                            int* __restrict__ edge_src) {
    int e4 = blockIdx.x * blockDim.x + threadIdx.x;
    if (e4 >= N_EDGES / 4) return;
    int4 s = ((const int4*)src)[e4];
    int4 d = ((const int4*)dst)[e4];
    int4 r = ((const int4*)rank)[e4];
    edge_src[row_start[d.x] + r.x] = s.x;
    edge_src[row_start[d.y] + r.y] = s.y;
    edge_src[row_start[d.z] + r.z] = s.z;
    edge_src[row_start[d.w] + r.w] = s.w;
}

// ---------- layer 1: gather(din=3) + MLP, one wave per node, bf16 out ----------
__global__ __launch_bounds__(256) void gin_layer3_kernel(
    const float* __restrict__ x, const int* __restrict__ row_start,
    const int* __restrict__ edge_src,
    const float* __restrict__ w1, const float* __restrict__ b1,
    const float* __restrict__ bn_g, const float* __restrict__ bn_b,
    const float* __restrict__ bn_m, const float* __restrict__ bn_v,
    const float* __restrict__ w2, const float* __restrict__ b2,
    __hip_bfloat16* __restrict__ hout) {
    __shared__ float s_w1[3 * H];
    __shared__ float s_w2[H * H];
    __shared__ float s_mid[4][H];
    __shared__ float s_scale[H], s_shift[H], s_b1[H], s_b2[H];

    int tid = threadIdx.x;
    for (int i = tid; i < 3 * H; i += 256) s_w1[i] = w1[i];
    for (int i = tid; i < H * H; i += 256) s_w2[i] = w2[i];
    if (tid < H) {
        float sc = rsqrtf(bn_v[tid] + BN_EPS) * bn_g[tid];
        s_scale[tid] = sc;
        s_shift[tid] = bn_b[tid] - bn_m[tid] * sc;
        s_b1[tid] = b1[tid];
        s_b2[tid] = b2[tid];
    }
    __syncthreads();

    int wave = tid >> 6;
    int j = tid & 63;
    int node = blockIdx.x * 4 + wave;

    int rs = row_start[node], re = row_start[node + 1];
    float a0 = 0.f, a1 = 0.f, a2 = 0.f;
    for (int t = rs + j; t < re; t += 64) {
        int s = edge_src[t];
        a0 += x[s * 3 + 0];
        a1 += x[s * 3 + 1];
        a2 += x[s * 3 + 2];
    }
#pragma unroll
    for (int off = 32; off > 0; off >>= 1) {
        a0 += __shfl_xor(a0, off);
        a1 += __shfl_xor(a1, off);
        a2 += __shfl_xor(a2, off);
    }
    float in0 = a0 + x[node * 3 + 0];
    float in1 = a1 + x[node * 3 + 1];
    float in2 = a2 + x[node * 3 + 2];

    float m = s_b1[j] + in0 * s_w1[0 * H + j] + in1 * s_w1[1 * H + j] + in2 * s_w1[2 * H + j];
    m = m * s_scale[j] + s_shift[j];
    m = fmaxf(m, 0.f);
    s_mid[wave][j] = m;
    __syncthreads();
    float o = s_b2[j];
#pragma unroll
    for (int k = 0; k < H; k++) o += s_mid[wave][k] * s_w2[k * H + j];
    o = fmaxf(o, 0.f);
    hout[(size_t)node * H + j] = __float2bfloat16(o);
}

// ---------- layers 2/3: packed bf16x2 gather + MLP, one wave per node ----------
// lanes 0-31 process even edges, lanes 32-63 odd edges; each lane loads a
// bf16x2 (features 2*jm, 2*jm+1). One load instruction covers TWO edges.
__global__ __launch_bounds__(512) void gin_layer64_kernel(
    const __hip_bfloat16* __restrict__ hin, const int* __restrict__ row_start,
    const int* __restrict__ edge_src,
    const float* __restrict__ w1, const float* __restrict__ b1,
    const float* __restrict__ bn_g, const float* __restrict__ bn_b,
    const float* __restrict__ bn_m, const float* __restrict__ bn_v,
    const float* __restrict__ w2, const float* __restrict__ b2,
    __hip_bfloat16* __restrict__ hout) {
    __shared__ float s_w1[H * H];
    __shared__ float s_w2[H * H];
    __shared__ float s_in[8][H];
    __shared__ float s_mid[8][H];
    __shared__ float s_scale[H], s_shift[H], s_b1[H], s_b2[H];

    int tid = threadIdx.x;
    for (int i = tid; i < H * H; i += 512) { s_w1[i] = w1[i]; s_w2[i] = w2[i]; }
    if (tid < H) {
        float sc = rsqrtf(bn_v[tid] + BN_EPS) * bn_g[tid];
        s_scale[tid] = sc;
        s_shift[tid] = bn_b[tid] - bn_m[tid] * sc;
        s_b1[tid] = b1[tid];
        s_b2[tid] = b2[tid];
    }
    __syncthreads();

    int wave = tid >> 6;
    int j = tid & 63;
    int half = j >> 5;    // 0: even edges, 1: odd edges
    int jm = j & 31;      // feature pair index
    int node = blockIdx.x * 8 + wave;

    const __hip_bfloat162* hin2 = (const __hip_bfloat162*)hin;
    int rs = row_start[node], re = row_start[node + 1];
    float ax = 0.f, ay = 0.f, bx = 0.f, by = 0.f;
    for (int base = rs; base < re; base += 64) {
        int idx = base + j;
        int sv = (idx < re) ? edge_src[idx] : 0;   // coalesced chunk of edge ids
        int cnt = min(64, re - base);
        int i = 0;
        for (; i + 3 < cnt; i += 4) {              // 4 edges per iter (2 per half)
            int s0 = __shfl(sv, i + half);
            int s1 = __shfl(sv, i + 2 + half);
            __hip_bfloat162 v0 = hin2[(size_t)s0 * 32 + jm];
            __hip_bfloat162 v1 = hin2[(size_t)s1 * 32 + jm];
            ax += __low2float(v0); ay += __high2float(v0);
            bx += __low2float(v1); by += __high2float(v1);
        }
        for (; i + 1 < cnt; i += 2) {              // leftover pair
            int s0 = __shfl(sv, i + half);
            __hip_bfloat162 v0 = hin2[(size_t)s0 * 32 + jm];
            ax += __low2float(v0); ay += __high2float(v0);
        }
        if (i < cnt) {                             // odd tail: only half 0 adds
            int s0 = __shfl(sv, i);
            __hip_bfloat162 v0 = hin2[(size_t)s0 * 32 + jm];
            float vx = __low2float(v0), vy = __high2float(v0);
            if (half == 0) { ax += vx; ay += vy; }
        }
    }
    ax += bx; ay += by;
    ax += __shfl_xor(ax, 32);
    ay += __shfl_xor(ay, 32);
    __hip_bfloat162 vself = hin2[(size_t)node * 32 + jm];
    if (half == 0) {
        s_in[wave][2 * jm]     = ax + __low2float(vself);
        s_in[wave][2 * jm + 1] = ay + __high2float(vself);
    }
    __syncthreads();

    float m = s_b1[j];
#pragma unroll
    for (int k = 0; k < H; k++) m += s_in[wave][k] * s_w1[k * H + j];
    m = m * s_scale[j] + s_shift[j];
    m = fmaxf(m, 0.f);
    s_mid[wave][j] = m;
    __syncthreads();

    float o = s_b2[j];
#pragma unroll
    for (int k = 0; k < H; k++) o += s_mid[wave][k] * s_w2[k * H + j];
    o = fmaxf(o, 0.f);
    hout[(size_t)node * H + j] = __float2bfloat16(o);
}

// ---------- pool (batch sorted -> range per graph) + head ----------
__global__ __launch_bounds__(192) void pool_head_kernel(
    const __hip_bfloat16* __restrict__ h1, const __hip_bfloat16* __restrict__ h2,
    const __hip_bfloat16* __restrict__ h3, const int* __restrict__ batch,
    const float* __restrict__ lin1_w, const float* __restrict__ lin1_b,
    const float* __restrict__ lin2_w, const float* __restrict__ lin2_b,
    float* __restrict__ out) {
    __shared__ float s_row[3 * H];
    __shared__ float s_mid[3 * H];
    __shared__ float s_z[C_CLS];
    __shared__ int s_se[2];

    int g = blockIdx.x;
    int j = threadIdx.x;
    if (j < 2) {
        int target = g + j;
        int lo = 0, hi = N_NODES;
        while (lo < hi) {
            int mid = (lo + hi) >> 1;
            if (batch[mid] < target) lo = mid + 1; else hi = mid;
        }
        s_se[j] = lo;
    }
    __syncthreads();
    int ns = s_se[0], ne = s_se[1];

    int which = j >> 6;       // 0,1,2
    int f = j & 63;
    const __hip_bfloat16* h = (which == 0) ? h1 : ((which == 1) ? h2 : h3);
    float p0 = 0.f, p1 = 0.f, p2 = 0.f, p3 = 0.f;
    int n = ns;
    for (; n + 3 < ne; n += 4) {
        p0 += __bfloat162float(h[(size_t)n * H + f]);
        p1 += __bfloat162float(h[(size_t)(n + 1) * H + f]);
        p2 += __bfloat162float(h[(size_t)(n + 2) * H + f]);
        p3 += __bfloat162float(h[(size_t)(n + 3) * H + f]);
    }
    for (; n < ne; n++) p0 += __bfloat162float(h[(size_t)n * H + f]);
    s_row[j] = (p0 + p1) + (p2 + p3);
    __syncthreads();

    float acc = lin1_b[j];
    for (int k = 0; k < 3 * H; k++) acc += s_row[k] * lin1_w[k * (3 * H) + j];
    s_mid[j] = fmaxf(acc, 0.f);
    __syncthreads();

    if (j < C_CLS) {
        float z = lin2_b[j];
        for (int k = 0; k < 3 * H; k++) z += s_mid[k] * lin2_w[k * C_CLS + j];
        s_z[j] = z;
    }
    __syncthreads();
    if (j < C_CLS) {
        float z0 = s_z[0], z1 = s_z[1];
        float mx = fmaxf(z0, z1);
        float lse = mx + logf(expf(z0 - mx) + expf(z1 - mx));
        out[g * C_CLS + j] = s_z[j];
        out[G_GRAPHS * C_CLS + g * C_CLS + j] = s_z[j] - lse;
    }
}

extern "C" void kernel_launch(void* const* d_in, const int* in_sizes, int n_in,
                              void* d_out, int out_size, void* d_ws, size_t ws_size,
                              hipStream_t stream) {
    const float* x = (const float*)d_in[0];
    const float* cw1[3], *cb1[3], *cg[3], *cbb[3], *cm[3], *cv[3], *cw2[3], *cb2[3];
    for (int l = 0; l < 3; l++) {
        int b = 1 + 8 * l;
        cw1[l] = (const float*)d_in[b + 0];
        cb1[l] = (const float*)d_in[b + 1];
        cg[l]  = (const float*)d_in[b + 2];
        cbb[l] = (const float*)d_in[b + 3];
        cm[l]  = (const float*)d_in[b + 4];
        cv[l]  = (const float*)d_in[b + 5];
        cw2[l] = (const float*)d_in[b + 6];
        cb2[l] = (const float*)d_in[b + 7];
    }
    const float* lin1_w = (const float*)d_in[25];
    const float* lin1_b = (const float*)d_in[26];
    const float* lin2_w = (const float*)d_in[27];
    const float* lin2_b = (const float*)d_in[28];
    const int* edge_index = (const int*)d_in[29];
    const int* batch = (const int*)d_in[30];
    const int* src = edge_index;
    const int* dst = edge_index + N_EDGES;
    float* out = (float*)d_out;

    // workspace layout (int-aligned; h buffers 4B-aligned for bf16x2 loads)
    int* edge_src = (int*)d_ws;                     // E
    int* rank = edge_src + N_EDGES;                 // E
    int* count = rank + N_EDGES;                    // N
    int* row_start = count + N_NODES;               // N+1
    int* block_sums = row_start + N_NODES + 1;      // SCAN_BLOCKS
    __hip_bfloat16* h1 = (__hip_bfloat16*)(block_sums + SCAN_BLOCKS + 1);  // N*H
    __hip_bfloat16* h2 = h1 + (size_t)N_NODES * H;
    __hip_bfloat16* h3 = h2 + (size_t)N_NODES * H;

    // ---- build CSR (dst -> list of src) ----
    hipMemsetAsync(count, 0, N_NODES * sizeof(int), stream);
    hist_kernel<<<(N_EDGES / 4 + 255) / 256, 256, 0, stream>>>(dst, count, rank);
    scan_sums_kernel<<<SCAN_BLOCKS, 256, 0, stream>>>(count, block_sums);
    scan_offsets_kernel<<<1, 64, 0, stream>>>(block_sums, row_start);
    scan_final_kernel<<<SCAN_BLOCKS, 256, 0, stream>>>(count, block_sums, row_start);
    fill_kernel<<<(N_EDGES / 4 + 255) / 256, 256, 0, stream>>>(src, dst, rank, row_start, edge_src);

    // ---- layer 1 ----
    gin_layer3_kernel<<<N_NODES / 4, 256, 0, stream>>>(x, row_start, edge_src,
        cw1[0], cb1[0], cg[0], cbb[0], cm[0], cv[0], cw2[0], cb2[0], h1);
    // ---- layer 2 ----
    gin_layer64_kernel<<<N_NODES / 8, 512, 0, stream>>>(h1, row_start, edge_src,
        cw1[1], cb1[1], cg[1], cbb[1], cm[1], cv[1], cw2[1], cb2[1], h2);
    // ---- layer 3 ----
    gin_layer64_kernel<<<N_NODES / 8, 512, 0, stream>>>(h2, row_start, edge_src,
        cw1[2], cb1[2], cg[2], cbb[2], cm[2], cv[2], cw2[2], cb2[2], h3);
    // ---- pool + head ----
    pool_head_kernel<<<G_GRAPHS, 3 * H, 0, stream>>>(h1, h2, h3, batch,
        lin1_w, lin1_b, lin2_w, lin2_b, out);
}

// Round 6
// 415.243 us; speedup vs baseline: 1.2272x; 1.0240x over previous
//
#include <hip/hip_runtime.h>
#include <hip/hip_bf16.h>
#include <math.h>

#define N_NODES 50000
#define N_EDGES 1600000
#define H 64
#define G_GRAPHS 512
#define C_CLS 2
#define BN_EPS 1e-5f
#define CPAD 16   // one counter per 64B line to kill memory-side atomic line contention

#define SCAN_CHUNK 1024            // elements per scan block (256 thr x 4)
#define SCAN_BLOCKS ((N_NODES + SCAN_CHUNK - 1) / SCAN_CHUNK)   // 49

__device__ __forceinline__ float bflo(unsigned int u) { return __uint_as_float(u << 16); }
__device__ __forceinline__ float bfhi(unsigned int u) { return __uint_as_float(u & 0xffff0000u); }

// ---------- CSR build: histogram of dst + per-edge rank (4 edges/thread) ----------
__global__ void hist_kernel(const int* __restrict__ dst, int* __restrict__ count,
                            int* __restrict__ rank) {
    int e4 = blockIdx.x * blockDim.x + threadIdx.x;
    if (e4 >= N_EDGES / 4) return;
    int4 d = ((const int4*)dst)[e4];
    int4 r;
    r.x = atomicAdd(&count[d.x * CPAD], 1);
    r.y = atomicAdd(&count[d.y * CPAD], 1);
    r.z = atomicAdd(&count[d.z * CPAD], 1);
    r.w = atomicAdd(&count[d.w * CPAD], 1);
    ((int4*)rank)[e4] = r;
}

// ---------- scan pass 1: per-block sums ----------
__global__ __launch_bounds__(256) void scan_sums_kernel(const int* __restrict__ count,
                                                        int* __restrict__ block_sums) {
    __shared__ int s[256];
    int base = blockIdx.x * SCAN_CHUNK + threadIdx.x * 4;
    int sum = 0;
#pragma unroll
    for (int i = 0; i < 4; i++) {
        int idx = base + i;
        if (idx < N_NODES) sum += count[idx * CPAD];
    }
    s[threadIdx.x] = sum;
    __syncthreads();
    for (int off = 128; off > 0; off >>= 1) {
        if (threadIdx.x < off) s[threadIdx.x] += s[threadIdx.x + off];
        __syncthreads();
    }
    if (threadIdx.x == 0) block_sums[blockIdx.x] = s[0];
}

// ---------- scan pass 2: exclusive scan of block sums (small) ----------
__global__ void scan_offsets_kernel(int* __restrict__ block_sums, int* __restrict__ row_start) {
    if (threadIdx.x == 0 && blockIdx.x == 0) {
        int acc = 0;
        for (int i = 0; i < SCAN_BLOCKS; i++) {
            int v = block_sums[i];
            block_sums[i] = acc;
            acc += v;
        }
        row_start[N_NODES] = N_EDGES;
    }
}

// ---------- scan pass 3: per-block exclusive scan ----------
__global__ __launch_bounds__(256) void scan_final_kernel(const int* __restrict__ count,
                                                         const int* __restrict__ block_sums,
                                                         int* __restrict__ row_start) {
    __shared__ int s[256];
    int base = blockIdx.x * SCAN_CHUNK + threadIdx.x * 4;
    int c[4], local[4];
    int sum = 0;
#pragma unroll
    for (int i = 0; i < 4; i++) {
        int idx = base + i;
        c[i] = (idx < N_NODES) ? count[idx * CPAD] : 0;
        local[i] = sum;
        sum += c[i];
    }
    s[threadIdx.x] = sum;
    __syncthreads();
    for (int off = 1; off < 256; off <<= 1) {
        int v = 0;
        if (threadIdx.x >= off) v = s[threadIdx.x - off];
        __syncthreads();
        if (threadIdx.x >= off) s[threadIdx.x] += v;
        __syncthreads();
    }
    int tprefix = s[threadIdx.x] - sum;
    int boff = block_sums[blockIdx.x];
#pragma unroll
    for (int i = 0; i < 4; i++) {
        int idx = base + i;
        if (idx < N_NODES) row_start[idx] = boff + tprefix + local[i];
    }
}

// ---------- CSR fill (atomic-free, 4 edges/thread) ----------
__global__ void fill_kernel(const int* __restrict__ src, const int* __restrict__ dst,
                            const int* __restrict__ rank, const int* __restrict__ row_start,
                            int* __restrict__ edge_src) {
    int e4 = blockIdx.x * blockDim.x + threadIdx.x;
    if (e4 >= N_EDGES / 4) return;
    int4 s = ((const int4*)src)[e4];
    int4 d = ((const int4*)dst)[e4];
    int4 r = ((const int4*)rank)[e4];
    edge_src[row_start[d.x] + r.x] = s.x;
    edge_src[row_start[d.y] + r.y] = s.y;
    edge_src[row_start[d.z] + r.z] = s.z;
    edge_src[row_start[d.w] + r.w] = s.w;
}

// ---------- layer 1: gather(din=3) + MLP, one wave per node, bf16 out ----------
__global__ __launch_bounds__(256) void gin_layer3_kernel(
    const float* __restrict__ x, const int* __restrict__ row_start,
    const int* __restrict__ edge_src,
    const float* __restrict__ w1, const float* __restrict__ b1,
    const float* __restrict__ bn_g, const float* __restrict__ bn_b,
    const float* __restrict__ bn_m, const float* __restrict__ bn_v,
    const float* __restrict__ w2, const float* __restrict__ b2,
    __hip_bfloat16* __restrict__ hout) {
    __shared__ float s_w1[3 * H];
    __shared__ float s_w2[H * H];
    __shared__ float s_mid[4][H];
    __shared__ float s_scale[H], s_shift[H], s_b1[H], s_b2[H];

    int tid = threadIdx.x;
    for (int i = tid; i < 3 * H; i += 256) s_w1[i] = w1[i];
    for (int i = tid; i < H * H; i += 256) s_w2[i] = w2[i];
    if (tid < H) {
        float sc = rsqrtf(bn_v[tid] + BN_EPS) * bn_g[tid];
        s_scale[tid] = sc;
        s_shift[tid] = bn_b[tid] - bn_m[tid] * sc;
        s_b1[tid] = b1[tid];
        s_b2[tid] = b2[tid];
    }
    __syncthreads();

    int wave = tid >> 6;
    int j = tid & 63;
    int node = blockIdx.x * 4 + wave;

    int rs = row_start[node], re = row_start[node + 1];
    float a0 = 0.f, a1 = 0.f, a2 = 0.f;
    for (int t = rs + j; t < re; t += 64) {
        int s = edge_src[t];
        a0 += x[s * 3 + 0];
        a1 += x[s * 3 + 1];
        a2 += x[s * 3 + 2];
    }
#pragma unroll
    for (int off = 32; off > 0; off >>= 1) {
        a0 += __shfl_xor(a0, off);
        a1 += __shfl_xor(a1, off);
        a2 += __shfl_xor(a2, off);
    }
    float in0 = a0 + x[node * 3 + 0];
    float in1 = a1 + x[node * 3 + 1];
    float in2 = a2 + x[node * 3 + 2];

    float m = s_b1[j] + in0 * s_w1[0 * H + j] + in1 * s_w1[1 * H + j] + in2 * s_w1[2 * H + j];
    m = m * s_scale[j] + s_shift[j];
    m = fmaxf(m, 0.f);
    s_mid[wave][j] = m;
    __syncthreads();
    float o = s_b2[j];
#pragma unroll
    for (int k = 0; k < H; k++) o += s_mid[wave][k] * s_w2[k * H + j];
    o = fmaxf(o, 0.f);
    hout[(size_t)node * H + j] = __float2bfloat16(o);
}

// ---------- layers 2/3: dwordx2 (4-feature) gather + MLP, one wave per node ----------
// quarter q = lane>>4 handles edge i+q; lane loads 8B = 4 features of that edge's row.
// One load instruction covers FOUR edges. Cross-quarter reduce via shfl_xor(16/32).
__global__ __launch_bounds__(512) void gin_layer64_kernel(
    const __hip_bfloat16* __restrict__ hin, const int* __restrict__ row_start,
    const int* __restrict__ edge_src,
    const float* __restrict__ w1, const float* __restrict__ b1,
    const float* __restrict__ bn_g, const float* __restrict__ bn_b,
    const float* __restrict__ bn_m, const float* __restrict__ bn_v,
    const float* __restrict__ w2, const float* __restrict__ b2,
    __hip_bfloat16* __restrict__ hout) {
    __shared__ float s_w1[H * H];
    __shared__ float s_w2[H * H];
    __shared__ float s_in[8][H];
    __shared__ float s_mid[8][H];
    __shared__ float s_scale[H], s_shift[H], s_b1[H], s_b2[H];

    int tid = threadIdx.x;
    for (int i = tid; i < H * H; i += 512) { s_w1[i] = w1[i]; s_w2[i] = w2[i]; }
    if (tid < H) {
        float sc = rsqrtf(bn_v[tid] + BN_EPS) * bn_g[tid];
        s_scale[tid] = sc;
        s_shift[tid] = bn_b[tid] - bn_m[tid] * sc;
        s_b1[tid] = b1[tid];
        s_b2[tid] = b2[tid];
    }
    __syncthreads();

    int wave = tid >> 6;
    int j = tid & 63;
    int q = j >> 4;       // 0..3: which edge of the group of 4
    int jf = j & 15;      // feature quad: features 4*jf .. 4*jf+3
    int node = blockIdx.x * 8 + wave;

    const char* hbase = (const char*)hin;
    int rs = row_start[node], re = row_start[node + 1];
    float a0 = 0.f, a1 = 0.f, a2 = 0.f, a3 = 0.f;
    for (int base = rs; base < re; base += 64) {
        int idx = base + j;
        int sv = (idx < re) ? edge_src[idx] : 0;   // coalesced chunk of edge ids
        int cnt = min(64, re - base);
        int i = 0;
        for (; i + 4 <= cnt; i += 4) {             // 4 edges per iter, 1 load/lane
            int s = __shfl(sv, i + q);
            uint2 raw = *(const uint2*)(hbase + (size_t)s * 128 + jf * 8);
            a0 += bflo(raw.x); a1 += bfhi(raw.x);
            a2 += bflo(raw.y); a3 += bfhi(raw.y);
        }
        if (i < cnt) {                             // tail: 1-3 edges
            int r = cnt - i;
            int s = __shfl(sv, i + (q < r ? q : 0));
            uint2 raw = *(const uint2*)(hbase + (size_t)s * 128 + jf * 8);
            if (q < r) {
                a0 += bflo(raw.x); a1 += bfhi(raw.x);
                a2 += bflo(raw.y); a3 += bfhi(raw.y);
            }
        }
    }
    // reduce across quarters (lanes with equal jf)
    a0 += __shfl_xor(a0, 16); a0 += __shfl_xor(a0, 32);
    a1 += __shfl_xor(a1, 16); a1 += __shfl_xor(a1, 32);
    a2 += __shfl_xor(a2, 16); a2 += __shfl_xor(a2, 32);
    a3 += __shfl_xor(a3, 16); a3 += __shfl_xor(a3, 32);
    if (q == 0) {
        uint2 raw = *(const uint2*)(hbase + (size_t)node * 128 + jf * 8);
        float4 v;
        v.x = a0 + bflo(raw.x); v.y = a1 + bfhi(raw.x);
        v.z = a2 + bflo(raw.y); v.w = a3 + bfhi(raw.y);
        ((float4*)s_in[wave])[jf] = v;
    }
    __syncthreads();

    float m = s_b1[j];
#pragma unroll
    for (int k = 0; k < H; k++) m += s_in[wave][k] * s_w1[k * H + j];
    m = m * s_scale[j] + s_shift[j];
    m = fmaxf(m, 0.f);
    s_mid[wave][j] = m;
    __syncthreads();

    float o = s_b2[j];
#pragma unroll
    for (int k = 0; k < H; k++) o += s_mid[wave][k] * s_w2[k * H + j];
    o = fmaxf(o, 0.f);
    hout[(size_t)node * H + j] = __float2bfloat16(o);
}

// ---------- pool (batch sorted -> range per graph) + head ----------
__global__ __launch_bounds__(192) void pool_head_kernel(
    const __hip_bfloat16* __restrict__ h1, const __hip_bfloat16* __restrict__ h2,
    const __hip_bfloat16* __restrict__ h3, const int* __restrict__ batch,
    const float* __restrict__ lin1_w, const float* __restrict__ lin1_b,
    const float* __restrict__ lin2_w, const float* __restrict__ lin2_b,
    float* __restrict__ out) {
    __shared__ float s_row[3 * H];
    __shared__ float s_mid[3 * H];
    __shared__ float s_z[C_CLS];
    __shared__ int s_se[2];

    int g = blockIdx.x;
    int j = threadIdx.x;
    if (j < 2) {
        int target = g + j;
        int lo = 0, hi = N_NODES;
        while (lo < hi) {
            int mid = (lo + hi) >> 1;
            if (batch[mid] < target) lo = mid + 1; else hi = mid;
        }
        s_se[j] = lo;
    }
    __syncthreads();
    int ns = s_se[0], ne = s_se[1];

    int which = j >> 6;       // 0,1,2
    int f = j & 63;
    const __hip_bfloat16* h = (which == 0) ? h1 : ((which == 1) ? h2 : h3);
    float p0 = 0.f, p1 = 0.f, p2 = 0.f, p3 = 0.f;
    int n = ns;
    for (; n + 3 < ne; n += 4) {
        p0 += __bfloat162float(h[(size_t)n * H + f]);
        p1 += __bfloat162float(h[(size_t)(n + 1) * H + f]);
        p2 += __bfloat162float(h[(size_t)(n + 2) * H + f]);
        p3 += __bfloat162float(h[(size_t)(n + 3) * H + f]);
    }
    for (; n < ne; n++) p0 += __bfloat162float(h[(size_t)n * H + f]);
    s_row[j] = (p0 + p1) + (p2 + p3);
    __syncthreads();

    float acc = lin1_b[j];
    for (int k = 0; k < 3 * H; k++) acc += s_row[k] * lin1_w[k * (3 * H) + j];
    s_mid[j] = fmaxf(acc, 0.f);
    __syncthreads();

    if (j < C_CLS) {
        float z = lin2_b[j];
        for (int k = 0; k < 3 * H; k++) z += s_mid[k] * lin2_w[k * C_CLS + j];
        s_z[j] = z;
    }
    __syncthreads();
    if (j < C_CLS) {
        float z0 = s_z[0], z1 = s_z[1];
        float mx = fmaxf(z0, z1);
        float lse = mx + logf(expf(z0 - mx) + expf(z1 - mx));
        out[g * C_CLS + j] = s_z[j];
        out[G_GRAPHS * C_CLS + g * C_CLS + j] = s_z[j] - lse;
    }
}

extern "C" void kernel_launch(void* const* d_in, const int* in_sizes, int n_in,
                              void* d_out, int out_size, void* d_ws, size_t ws_size,
                              hipStream_t stream) {
    const float* x = (const float*)d_in[0];
    const float* cw1[3], *cb1[3], *cg[3], *cbb[3], *cm[3], *cv[3], *cw2[3], *cb2[3];
    for (int l = 0; l < 3; l++) {
        int b = 1 + 8 * l;
        cw1[l] = (const float*)d_in[b + 0];
        cb1[l] = (const float*)d_in[b + 1];
        cg[l]  = (const float*)d_in[b + 2];
        cbb[l] = (const float*)d_in[b + 3];
        cm[l]  = (const float*)d_in[b + 4];
        cv[l]  = (const float*)d_in[b + 5];
        cw2[l] = (const float*)d_in[b + 6];
        cb2[l] = (const float*)d_in[b + 7];
    }
    const float* lin1_w = (const float*)d_in[25];
    const float* lin1_b = (const float*)d_in[26];
    const float* lin2_w = (const float*)d_in[27];
    const float* lin2_b = (const float*)d_in[28];
    const int* edge_index = (const int*)d_in[29];
    const int* batch = (const int*)d_in[30];
    const int* src = edge_index;
    const int* dst = edge_index + N_EDGES;
    float* out = (float*)d_out;

    // workspace layout
    int* edge_src = (int*)d_ws;                     // E
    int* rank = edge_src + N_EDGES;                 // E
    int* count = rank + N_EDGES;                    // N*CPAD (padded: 1 counter / 64B line)
    int* row_start = count + N_NODES * CPAD;        // N+1
    int* block_sums = row_start + N_NODES + 2;      // SCAN_BLOCKS
    uintptr_t hp = (uintptr_t)(block_sums + SCAN_BLOCKS);
    hp = (hp + 127) & ~(uintptr_t)127;              // 128B-align h buffers
    __hip_bfloat16* h1 = (__hip_bfloat16*)hp;       // N*H
    __hip_bfloat16* h2 = h1 + (size_t)N_NODES * H;
    __hip_bfloat16* h3 = h2 + (size_t)N_NODES * H;

    // ---- build CSR (dst -> list of src) ----
    hipMemsetAsync(count, 0, (size_t)N_NODES * CPAD * sizeof(int), stream);
    hist_kernel<<<(N_EDGES / 4 + 255) / 256, 256, 0, stream>>>(dst, count, rank);
    scan_sums_kernel<<<SCAN_BLOCKS, 256, 0, stream>>>(count, block_sums);
    scan_offsets_kernel<<<1, 64, 0, stream>>>(block_sums, row_start);
    scan_final_kernel<<<SCAN_BLOCKS, 256, 0, stream>>>(count, block_sums, row_start);
    fill_kernel<<<(N_EDGES / 4 + 255) / 256, 256, 0, stream>>>(src, dst, rank, row_start, edge_src);

    // ---- layer 1 ----
    gin_layer3_kernel<<<N_NODES / 4, 256, 0, stream>>>(x, row_start, edge_src,
        cw1[0], cb1[0], cg[0], cbb[0], cm[0], cv[0], cw2[0], cb2[0], h1);
    // ---- layer 2 ----
    gin_layer64_kernel<<<N_NODES / 8, 512, 0, stream>>>(h1, row_start, edge_src,
        cw1[1], cb1[1], cg[1], cbb[1], cm[1], cv[1], cw2[1], cb2[1], h2);
    // ---- layer 3 ----
    gin_layer64_kernel<<<N_NODES / 8, 512, 0, stream>>>(h2, row_start, edge_src,
        cw1[2], cb1[2], cg[2], cbb[2], cm[2], cv[2], cw2[2], cb2[2], h3);
    // ---- pool + head ----
    pool_head_kernel<<<G_GRAPHS, 3 * H, 0, stream>>>(h1, h2, h3, batch,
        lin1_w, lin1_b, lin2_w, lin2_b, out);
}

// Round 7
// 365.665 us; speedup vs baseline: 1.3936x; 1.1356x over previous
//
#include <hip/hip_runtime.h>
#include <hip/hip_bf16.h>
#include <math.h>

#define N_NODES 50000
#define N_EDGES 1600000
#define H 64
#define G_GRAPHS 512
#define C_CLS 2
#define BN_EPS 1e-5f
#define CPAD 16   // one counter per 64B line to kill memory-side atomic line contention
#define IOP 72    // padded LDS row (bf16 elems) -> 144B stride, breaks b128 phase conflicts

#define SCAN_CHUNK 1024
#define SCAN_BLOCKS ((N_NODES + SCAN_CHUNK - 1) / SCAN_CHUNK)   // 49

typedef __attribute__((ext_vector_type(8))) short short8;
typedef __attribute__((ext_vector_type(4))) float floatx4;

__device__ __forceinline__ float bflo(unsigned int u) { return __uint_as_float(u << 16); }
__device__ __forceinline__ float bfhi(unsigned int u) { return __uint_as_float(u & 0xffff0000u); }
__device__ __forceinline__ unsigned short bf16_rne(float f) {
    unsigned int u = __float_as_uint(f);
    u += 0x7fffu + ((u >> 16) & 1u);
    return (unsigned short)(u >> 16);
}

// ---------- CSR build: histogram of dst + per-edge rank (4 edges/thread) ----------
__global__ void hist_kernel(const int* __restrict__ dst, int* __restrict__ count,
                            int* __restrict__ rank) {
    int e4 = blockIdx.x * blockDim.x + threadIdx.x;
    if (e4 >= N_EDGES / 4) return;
    int4 d = ((const int4*)dst)[e4];
    int4 r;
    r.x = atomicAdd(&count[d.x * CPAD], 1);
    r.y = atomicAdd(&count[d.y * CPAD], 1);
    r.z = atomicAdd(&count[d.z * CPAD], 1);
    r.w = atomicAdd(&count[d.w * CPAD], 1);
    ((int4*)rank)[e4] = r;
}

// ---------- scan pass 1: per-block sums ----------
__global__ __launch_bounds__(256) void scan_sums_kernel(const int* __restrict__ count,
                                                        int* __restrict__ block_sums) {
    __shared__ int s[256];
    int base = blockIdx.x * SCAN_CHUNK + threadIdx.x * 4;
    int sum = 0;
#pragma unroll
    for (int i = 0; i < 4; i++) {
        int idx = base + i;
        if (idx < N_NODES) sum += count[idx * CPAD];
    }
    s[threadIdx.x] = sum;
    __syncthreads();
    for (int off = 128; off > 0; off >>= 1) {
        if (threadIdx.x < off) s[threadIdx.x] += s[threadIdx.x + off];
        __syncthreads();
    }
    if (threadIdx.x == 0) block_sums[blockIdx.x] = s[0];
}

// ---------- scan pass 2 ----------
__global__ void scan_offsets_kernel(int* __restrict__ block_sums, int* __restrict__ row_start) {
    if (threadIdx.x == 0 && blockIdx.x == 0) {
        int acc = 0;
        for (int i = 0; i < SCAN_BLOCKS; i++) {
            int v = block_sums[i];
            block_sums[i] = acc;
            acc += v;
        }
        row_start[N_NODES] = N_EDGES;
    }
}

// ---------- scan pass 3 ----------
__global__ __launch_bounds__(256) void scan_final_kernel(const int* __restrict__ count,
                                                         const int* __restrict__ block_sums,
                                                         int* __restrict__ row_start) {
    __shared__ int s[256];
    int base = blockIdx.x * SCAN_CHUNK + threadIdx.x * 4;
    int c[4], local[4];
    int sum = 0;
#pragma unroll
    for (int i = 0; i < 4; i++) {
        int idx = base + i;
        c[i] = (idx < N_NODES) ? count[idx * CPAD] : 0;
        local[i] = sum;
        sum += c[i];
    }
    s[threadIdx.x] = sum;
    __syncthreads();
    for (int off = 1; off < 256; off <<= 1) {
        int v = 0;
        if (threadIdx.x >= off) v = s[threadIdx.x - off];
        __syncthreads();
        if (threadIdx.x >= off) s[threadIdx.x] += v;
        __syncthreads();
    }
    int tprefix = s[threadIdx.x] - sum;
    int boff = block_sums[blockIdx.x];
#pragma unroll
    for (int i = 0; i < 4; i++) {
        int idx = base + i;
        if (idx < N_NODES) row_start[idx] = boff + tprefix + local[i];
    }
}

// ---------- CSR fill (atomic-free, 4 edges/thread) ----------
__global__ void fill_kernel(const int* __restrict__ src, const int* __restrict__ dst,
                            const int* __restrict__ rank, const int* __restrict__ row_start,
                            int* __restrict__ edge_src) {
    int e4 = blockIdx.x * blockDim.x + threadIdx.x;
    if (e4 >= N_EDGES / 4) return;
    int4 s = ((const int4*)src)[e4];
    int4 d = ((const int4*)dst)[e4];
    int4 r = ((const int4*)rank)[e4];
    edge_src[row_start[d.x] + r.x] = s.x;
    edge_src[row_start[d.y] + r.y] = s.y;
    edge_src[row_start[d.z] + r.z] = s.z;
    edge_src[row_start[d.w] + r.w] = s.w;
}

// ---------- layer 1: gather(din=3) + MLP, one wave per node, bf16 out ----------
__global__ __launch_bounds__(256) void gin_layer3_kernel(
    const float* __restrict__ x, const int* __restrict__ row_start,
    const int* __restrict__ edge_src,
    const float* __restrict__ w1, const float* __restrict__ b1,
    const float* __restrict__ bn_g, const float* __restrict__ bn_b,
    const float* __restrict__ bn_m, const float* __restrict__ bn_v,
    const float* __restrict__ w2, const float* __restrict__ b2,
    __hip_bfloat16* __restrict__ hout) {
    __shared__ float s_w1[3 * H];
    __shared__ float s_w2[H * H];
    __shared__ float s_mid[4][H];
    __shared__ float s_scale[H], s_shift[H], s_b1[H], s_b2[H];

    int tid = threadIdx.x;
    for (int i = tid; i < 3 * H; i += 256) s_w1[i] = w1[i];
    for (int i = tid; i < H * H; i += 256) s_w2[i] = w2[i];
    if (tid < H) {
        float sc = rsqrtf(bn_v[tid] + BN_EPS) * bn_g[tid];
        s_scale[tid] = sc;
        s_shift[tid] = bn_b[tid] - bn_m[tid] * sc;
        s_b1[tid] = b1[tid];
        s_b2[tid] = b2[tid];
    }
    __syncthreads();

    int wave = tid >> 6;
    int j = tid & 63;
    int node = blockIdx.x * 4 + wave;

    int rs = row_start[node], re = row_start[node + 1];
    float a0 = 0.f, a1 = 0.f, a2 = 0.f;
    for (int t = rs + j; t < re; t += 64) {
        int s = edge_src[t];
        a0 += x[s * 3 + 0];
        a1 += x[s * 3 + 1];
        a2 += x[s * 3 + 2];
    }
#pragma unroll
    for (int off = 32; off > 0; off >>= 1) {
        a0 += __shfl_xor(a0, off);
        a1 += __shfl_xor(a1, off);
        a2 += __shfl_xor(a2, off);
    }
    float in0 = a0 + x[node * 3 + 0];
    float in1 = a1 + x[node * 3 + 1];
    float in2 = a2 + x[node * 3 + 2];

    float m = s_b1[j] + in0 * s_w1[0 * H + j] + in1 * s_w1[1 * H + j] + in2 * s_w1[2 * H + j];
    m = m * s_scale[j] + s_shift[j];
    m = fmaxf(m, 0.f);
    s_mid[wave][j] = m;
    __syncthreads();
    float o = s_b2[j];
#pragma unroll
    for (int k = 0; k < H; k++) o += s_mid[wave][k] * s_w2[k * H + j];
    o = fmaxf(o, 0.f);
    hout[(size_t)node * H + j] = __float2bfloat16(o);
}

// ---------- pure gather: xs[n] = h[n] + sum_{j->n} h[j], bf16, no LDS ----------
__global__ __launch_bounds__(512) void gather_kernel(
    const __hip_bfloat16* __restrict__ hin, const int* __restrict__ row_start,
    const int* __restrict__ edge_src, __hip_bfloat16* __restrict__ xs) {
    int tid = threadIdx.x;
    int wave = tid >> 6;
    int j = tid & 63;
    int q = j >> 4;
    int jf = j & 15;
    int node = blockIdx.x * 8 + wave;   // grid exactly covers N

    const char* hbase = (const char*)hin;
    int rs = row_start[node], re = row_start[node + 1];
    float a0 = 0.f, a1 = 0.f, a2 = 0.f, a3 = 0.f;
    for (int base = rs; base < re; base += 64) {
        int idx = base + j;
        int sv = (idx < re) ? edge_src[idx] : 0;
        int cnt = min(64, re - base);
        int i = 0;
        for (; i + 4 <= cnt; i += 4) {
            int s = __shfl(sv, i + q);
            uint2 raw = *(const uint2*)(hbase + (size_t)s * 128 + jf * 8);
            a0 += bflo(raw.x); a1 += bfhi(raw.x);
            a2 += bflo(raw.y); a3 += bfhi(raw.y);
        }
        if (i < cnt) {
            int r = cnt - i;
            int s = __shfl(sv, i + (q < r ? q : 0));
            uint2 raw = *(const uint2*)(hbase + (size_t)s * 128 + jf * 8);
            if (q < r) { a0 += bflo(raw.x); a1 += bfhi(raw.x); a2 += bflo(raw.y); a3 += bfhi(raw.y); }
        }
    }
    a0 += __shfl_xor(a0, 16); a0 += __shfl_xor(a0, 32);
    a1 += __shfl_xor(a1, 16); a1 += __shfl_xor(a1, 32);
    a2 += __shfl_xor(a2, 16); a2 += __shfl_xor(a2, 32);
    a3 += __shfl_xor(a3, 16); a3 += __shfl_xor(a3, 32);
    if (q == 0) {
        uint2 raw = *(const uint2*)(hbase + (size_t)node * 128 + jf * 8);
        a0 += bflo(raw.x); a1 += bfhi(raw.x);
        a2 += bflo(raw.y); a3 += bfhi(raw.y);
        uint2 o;
        o.x = (unsigned int)bf16_rne(a0) | ((unsigned int)bf16_rne(a1) << 16);
        o.y = (unsigned int)bf16_rne(a2) | ((unsigned int)bf16_rne(a3) << 16);
        *(uint2*)((char*)xs + (size_t)node * 128 + jf * 8) = o;
    }
}

// ---------- batched MFMA MLP: hout = relu(relu_bn(xs@w1+b1)@w2+b2) ----------
// 256 thr = 4 waves, 16 nodes/wave (MFMA M=16), 64 nodes/block.
// A-frag: lane holds A[m=lane&15][k=quad*8+t]; B-frag from transposed wT[j][k];
// C/D: col=lane&15 (=j), row=quad*4+reg (=node).
__global__ __launch_bounds__(256) void mlp_mfma_kernel(
    const __hip_bfloat16* __restrict__ xs,
    const float* __restrict__ w1, const float* __restrict__ b1,
    const float* __restrict__ bn_g, const float* __restrict__ bn_b,
    const float* __restrict__ bn_m, const float* __restrict__ bn_v,
    const float* __restrict__ w2, const float* __restrict__ b2,
    __hip_bfloat16* __restrict__ hout) {
    __shared__ unsigned short s_w1t[H * IOP];
    __shared__ unsigned short s_w2t[H * IOP];
    __shared__ unsigned short s_mid[4][16 * IOP];
    __shared__ unsigned short s_out[4][16 * IOP];

    int tid = threadIdx.x;
    for (int idx = tid; idx < H * H; idx += 256) {
        int k = idx >> 6, jj = idx & 63;         // coalesced read of w[k][j]
        s_w1t[jj * IOP + k] = bf16_rne(w1[idx]); // store transposed wT[j][k]
        s_w2t[jj * IOP + k] = bf16_rne(w2[idx]);
    }
    int lane = tid & 63, wave = tid >> 6;
    int quad = lane >> 4, l15 = lane & 15;
    float scl[4], sht[4], bb1[4], bb2[4];
#pragma unroll
    for (int jt = 0; jt < 4; jt++) {
        int j = jt * 16 + l15;
        float sc = rsqrtf(bn_v[j] + BN_EPS) * bn_g[j];
        scl[jt] = sc;
        sht[jt] = bn_b[j] - bn_m[j] * sc;
        bb1[jt] = b1[j];
        bb2[jt] = b2[j];
    }
    __syncthreads();

    int base = blockIdx.x * 64 + wave * 16;
    const unsigned short* xr = (const unsigned short*)xs;
    int am = min(base + l15, N_NODES - 1);       // clamp (stores are guarded)
    short8 a0 = *(const short8*)(xr + (size_t)am * H + quad * 8);
    short8 a1 = *(const short8*)(xr + (size_t)am * H + quad * 8 + 32);

    unsigned short* mid = s_mid[wave];
    unsigned short* outw = s_out[wave];

#pragma unroll
    for (int jt = 0; jt < 4; jt++) {
        short8 b0 = *(const short8*)&s_w1t[(jt * 16 + l15) * IOP + quad * 8];
        short8 bv = *(const short8*)&s_w1t[(jt * 16 + l15) * IOP + quad * 8 + 32];
        floatx4 c = {0.f, 0.f, 0.f, 0.f};
        c = __builtin_amdgcn_mfma_f32_16x16x32_bf16(a0, b0, c, 0, 0, 0);
        c = __builtin_amdgcn_mfma_f32_16x16x32_bf16(a1, bv, c, 0, 0, 0);
#pragma unroll
        for (int r = 0; r < 4; r++) {
            float v = (c[r] + bb1[jt]) * scl[jt] + sht[jt];
            v = fmaxf(v, 0.f);
            mid[(quad * 4 + r) * IOP + jt * 16 + l15] = bf16_rne(v);
        }
    }
    __syncthreads();   // cross-lane LDS RAW (C-layout -> A-layout transpose)

    short8 m0 = *(const short8*)&mid[l15 * IOP + quad * 8];
    short8 m1 = *(const short8*)&mid[l15 * IOP + quad * 8 + 32];
#pragma unroll
    for (int jt = 0; jt < 4; jt++) {
        short8 b0 = *(const short8*)&s_w2t[(jt * 16 + l15) * IOP + quad * 8];
        short8 bv = *(const short8*)&s_w2t[(jt * 16 + l15) * IOP + quad * 8 + 32];
        floatx4 c = {0.f, 0.f, 0.f, 0.f};
        c = __builtin_amdgcn_mfma_f32_16x16x32_bf16(m0, b0, c, 0, 0, 0);
        c = __builtin_amdgcn_mfma_f32_16x16x32_bf16(m1, bv, c, 0, 0, 0);
#pragma unroll
        for (int r = 0; r < 4; r++) {
            float v = fmaxf(c[r] + bb2[jt], 0.f);
            outw[(quad * 4 + r) * IOP + jt * 16 + l15] = bf16_rne(v);
        }
    }
    __syncthreads();   // cross-lane LDS RAW before coalesced store

    unsigned short* ho = (unsigned short*)hout;
#pragma unroll
    for (int cc = 0; cc < 2; cc++) {
        int r = cc * 8 + (lane >> 3);
        int node = base + r;
        if (node < N_NODES) {
            short8 v = *(const short8*)&outw[r * IOP + (lane & 7) * 8];
            *(short8*)(ho + (size_t)node * H + (lane & 7) * 8) = v;
        }
    }
}

// ---------- pool (batch sorted -> range per graph) + head ----------
__global__ __launch_bounds__(192) void pool_head_kernel(
    const __hip_bfloat16* __restrict__ h1, const __hip_bfloat16* __restrict__ h2,
    const __hip_bfloat16* __restrict__ h3, const int* __restrict__ batch,
    const float* __restrict__ lin1_w, const float* __restrict__ lin1_b,
    const float* __restrict__ lin2_w, const float* __restrict__ lin2_b,
    float* __restrict__ out) {
    __shared__ float s_row[3 * H];
    __shared__ float s_mid[3 * H];
    __shared__ float s_z[C_CLS];
    __shared__ int s_se[2];

    int g = blockIdx.x;
    int j = threadIdx.x;
    if (j < 2) {
        int target = g + j;
        int lo = 0, hi = N_NODES;
        while (lo < hi) {
            int mid = (lo + hi) >> 1;
            if (batch[mid] < target) lo = mid + 1; else hi = mid;
        }
        s_se[j] = lo;
    }
    __syncthreads();
    int ns = s_se[0], ne = s_se[1];

    int which = j >> 6;
    int f = j & 63;
    const __hip_bfloat16* h = (which == 0) ? h1 : ((which == 1) ? h2 : h3);
    float p0 = 0.f, p1 = 0.f, p2 = 0.f, p3 = 0.f;
    int n = ns;
    for (; n + 3 < ne; n += 4) {
        p0 += __bfloat162float(h[(size_t)n * H + f]);
        p1 += __bfloat162float(h[(size_t)(n + 1) * H + f]);
        p2 += __bfloat162float(h[(size_t)(n + 2) * H + f]);
        p3 += __bfloat162float(h[(size_t)(n + 3) * H + f]);
    }
    for (; n < ne; n++) p0 += __bfloat162float(h[(size_t)n * H + f]);
    s_row[j] = (p0 + p1) + (p2 + p3);
    __syncthreads();

    float acc = lin1_b[j];
    for (int k = 0; k < 3 * H; k++) acc += s_row[k] * lin1_w[k * (3 * H) + j];
    s_mid[j] = fmaxf(acc, 0.f);
    __syncthreads();

    if (j < C_CLS) {
        float z = lin2_b[j];
        for (int k = 0; k < 3 * H; k++) z += s_mid[k] * lin2_w[k * C_CLS + j];
        s_z[j] = z;
    }
    __syncthreads();
    if (j < C_CLS) {
        float z0 = s_z[0], z1 = s_z[1];
        float mx = fmaxf(z0, z1);
        float lse = mx + logf(expf(z0 - mx) + expf(z1 - mx));
        out[g * C_CLS + j] = s_z[j];
        out[G_GRAPHS * C_CLS + g * C_CLS + j] = s_z[j] - lse;
    }
}

extern "C" void kernel_launch(void* const* d_in, const int* in_sizes, int n_in,
                              void* d_out, int out_size, void* d_ws, size_t ws_size,
                              hipStream_t stream) {
    const float* x = (const float*)d_in[0];
    const float* cw1[3], *cb1[3], *cg[3], *cbb[3], *cm[3], *cv[3], *cw2[3], *cb2[3];
    for (int l = 0; l < 3; l++) {
        int b = 1 + 8 * l;
        cw1[l] = (const float*)d_in[b + 0];
        cb1[l] = (const float*)d_in[b + 1];
        cg[l]  = (const float*)d_in[b + 2];
        cbb[l] = (const float*)d_in[b + 3];
        cm[l]  = (const float*)d_in[b + 4];
        cv[l]  = (const float*)d_in[b + 5];
        cw2[l] = (const float*)d_in[b + 6];
        cb2[l] = (const float*)d_in[b + 7];
    }
    const float* lin1_w = (const float*)d_in[25];
    const float* lin1_b = (const float*)d_in[26];
    const float* lin2_w = (const float*)d_in[27];
    const float* lin2_b = (const float*)d_in[28];
    const int* edge_index = (const int*)d_in[29];
    const int* batch = (const int*)d_in[30];
    const int* src = edge_index;
    const int* dst = edge_index + N_EDGES;
    float* out = (float*)d_out;

    // workspace layout
    int* edge_src = (int*)d_ws;                     // E
    int* rank = edge_src + N_EDGES;                 // E
    int* count = rank + N_EDGES;                    // N*CPAD
    int* row_start = count + N_NODES * CPAD;        // N+2
    int* block_sums = row_start + N_NODES + 2;      // SCAN_BLOCKS
    uintptr_t hp = (uintptr_t)(block_sums + SCAN_BLOCKS);
    hp = (hp + 127) & ~(uintptr_t)127;
    __hip_bfloat16* h1 = (__hip_bfloat16*)hp;       // N*H each
    __hip_bfloat16* h2 = h1 + (size_t)N_NODES * H;
    __hip_bfloat16* h3 = h2 + (size_t)N_NODES * H;
    __hip_bfloat16* xs = h3 + (size_t)N_NODES * H;  // gather output (reused)

    // ---- build CSR ----
    hipMemsetAsync(count, 0, (size_t)N_NODES * CPAD * sizeof(int), stream);
    hist_kernel<<<(N_EDGES / 4 + 255) / 256, 256, 0, stream>>>(dst, count, rank);
    scan_sums_kernel<<<SCAN_BLOCKS, 256, 0, stream>>>(count, block_sums);
    scan_offsets_kernel<<<1, 64, 0, stream>>>(block_sums, row_start);
    scan_final_kernel<<<SCAN_BLOCKS, 256, 0, stream>>>(count, block_sums, row_start);
    fill_kernel<<<(N_EDGES / 4 + 255) / 256, 256, 0, stream>>>(src, dst, rank, row_start, edge_src);

    const int mlp_grid = (N_NODES + 63) / 64;   // 782

    // ---- layer 1 ----
    gin_layer3_kernel<<<N_NODES / 4, 256, 0, stream>>>(x, row_start, edge_src,
        cw1[0], cb1[0], cg[0], cbb[0], cm[0], cv[0], cw2[0], cb2[0], h1);
    // ---- layer 2 ----
    gather_kernel<<<N_NODES / 8, 512, 0, stream>>>(h1, row_start, edge_src, xs);
    mlp_mfma_kernel<<<mlp_grid, 256, 0, stream>>>(xs,
        cw1[1], cb1[1], cg[1], cbb[1], cm[1], cv[1], cw2[1], cb2[1], h2);
    // ---- layer 3 ----
    gather_kernel<<<N_NODES / 8, 512, 0, stream>>>(h2, row_start, edge_src, xs);
    mlp_mfma_kernel<<<mlp_grid, 256, 0, stream>>>(xs,
        cw1[2], cb1[2], cg[2], cbb[2], cm[2], cv[2], cw2[2], cb2[2], h3);
    // ---- pool + head ----
    pool_head_kernel<<<G_GRAPHS, 3 * H, 0, stream>>>(h1, h2, h3, batch,
        lin1_w, lin1_b, lin2_w, lin2_b, out);
}

// Round 8
// 329.893 us; speedup vs baseline: 1.5447x; 1.1084x over previous
//
#include <hip/hip_runtime.h>
#include <hip/hip_bf16.h>
#include <math.h>

#define N_NODES 50000
#define N_EDGES 1600000
#define H 64
#define G_GRAPHS 512
#define C_CLS 2
#define BN_EPS 1e-5f
#define NBUCK 196           // buckets of 256 nodes: dst>>8 in [0,196)
#define E4 (N_EDGES / 4)    // 400000
#define CSR_BLOCKS ((E4 + 511) / 512)   // 782, each handles 2048 edges

typedef __attribute__((ext_vector_type(8))) short short8;
typedef __attribute__((ext_vector_type(4))) float floatx4;

__device__ __forceinline__ float bflo(unsigned int u) { return __uint_as_float(u << 16); }
__device__ __forceinline__ float bfhi(unsigned int u) { return __uint_as_float(u & 0xffff0000u); }
__device__ __forceinline__ unsigned int bf16_rne(float f) {
    unsigned int u = __float_as_uint(f);
    u += 0x7fffu + ((u >> 16) & 1u);
    return u >> 16;
}

// ---------- CSR pass 1: global bucket histogram (LDS-privatized) ----------
__global__ __launch_bounds__(256) void bhist_kernel(const int* __restrict__ dst,
                                                    int* __restrict__ gbh) {
    __shared__ int bh[NBUCK];
    int t = threadIdx.x;
    if (t < NBUCK) bh[t] = 0;
    __syncthreads();
    int base = blockIdx.x * 512;
#pragma unroll
    for (int p = 0; p < 2; p++) {
        int i = base + p * 256 + t;
        if (i < E4) {
            int4 d = ((const int4*)dst)[i];
            atomicAdd(&bh[d.x >> 8], 1);
            atomicAdd(&bh[d.y >> 8], 1);
            atomicAdd(&bh[d.z >> 8], 1);
            atomicAdd(&bh[d.w >> 8], 1);
        }
    }
    __syncthreads();
    if (t < NBUCK && bh[t]) atomicAdd(&gbh[t], bh[t]);
}

// ---------- CSR pass 2: exclusive scan of 196 bucket counts ----------
__global__ __launch_bounds__(256) void bscan_kernel(const int* __restrict__ gbh,
                                                    int* __restrict__ bucket_start,
                                                    int* __restrict__ cursor,
                                                    int* __restrict__ row_start) {
    __shared__ int s[256];
    int t = threadIdx.x;
    int v = (t < NBUCK) ? gbh[t] : 0;
    s[t] = v;
    __syncthreads();
    for (int off = 1; off < 256; off <<= 1) {
        int u = 0;
        if (t >= off) u = s[t - off];
        __syncthreads();
        if (t >= off) s[t] += u;
        __syncthreads();
    }
    int excl = s[t] - v;
    if (t < NBUCK) { bucket_start[t] = excl; cursor[t] = excl; }
    if (t == 0) { bucket_start[NBUCK] = N_EDGES; row_start[N_NODES] = N_EDGES; }
}

// ---------- CSR pass 3: scatter edges into buckets (rank via LDS atomics) ----------
__global__ __launch_bounds__(256) void bscatter_kernel(const int* __restrict__ src,
                                                       const int* __restrict__ dst,
                                                       int* __restrict__ cursor,
                                                       int* __restrict__ gpacked) {
    __shared__ int bh[NBUCK];
    int t = threadIdx.x;
    if (t < NBUCK) bh[t] = 0;
    __syncthreads();
    int base = blockIdx.x * 512;

    int pkA[4], bkA[4], lrA[4]; bool vA = false;
    int pkB[4], bkB[4], lrB[4]; bool vB = false;
    {
        int i = base + t;
        if (i < E4) {
            vA = true;
            int4 s4 = ((const int4*)src)[i];
            int4 d4 = ((const int4*)dst)[i];
            bkA[0] = d4.x >> 8; pkA[0] = ((d4.x & 255) << 16) | s4.x; lrA[0] = atomicAdd(&bh[bkA[0]], 1);
            bkA[1] = d4.y >> 8; pkA[1] = ((d4.y & 255) << 16) | s4.y; lrA[1] = atomicAdd(&bh[bkA[1]], 1);
            bkA[2] = d4.z >> 8; pkA[2] = ((d4.z & 255) << 16) | s4.z; lrA[2] = atomicAdd(&bh[bkA[2]], 1);
            bkA[3] = d4.w >> 8; pkA[3] = ((d4.w & 255) << 16) | s4.w; lrA[3] = atomicAdd(&bh[bkA[3]], 1);
        }
    }
    {
        int i = base + 256 + t;
        if (i < E4) {
            vB = true;
            int4 s4 = ((const int4*)src)[i];
            int4 d4 = ((const int4*)dst)[i];
            bkB[0] = d4.x >> 8; pkB[0] = ((d4.x & 255) << 16) | s4.x; lrB[0] = atomicAdd(&bh[bkB[0]], 1);
            bkB[1] = d4.y >> 8; pkB[1] = ((d4.y & 255) << 16) | s4.y; lrB[1] = atomicAdd(&bh[bkB[1]], 1);
            bkB[2] = d4.z >> 8; pkB[2] = ((d4.z & 255) << 16) | s4.z; lrB[2] = atomicAdd(&bh[bkB[2]], 1);
            bkB[3] = d4.w >> 8; pkB[3] = ((d4.w & 255) << 16) | s4.w; lrB[3] = atomicAdd(&bh[bkB[3]], 1);
        }
    }
    __syncthreads();
    if (t < NBUCK) {
        int c = bh[t];
        bh[t] = c ? atomicAdd(&cursor[t], c) : 0;   // per-(block,bucket) base
    }
    __syncthreads();
    if (vA) {
#pragma unroll
        for (int q = 0; q < 4; q++) gpacked[bh[bkA[q]] + lrA[q]] = pkA[q];
    }
    if (vB) {
#pragma unroll
        for (int q = 0; q < 4; q++) gpacked[bh[bkB[q]] + lrB[q]] = pkB[q];
    }
}

// ---------- CSR pass 4: per-bucket local CSR (256 nodes/bucket) ----------
__global__ __launch_bounds__(256) void bcsr_kernel(const int* __restrict__ gpacked,
                                                   const int* __restrict__ bucket_start,
                                                   int* __restrict__ row_start,
                                                   int* __restrict__ edge_src) {
    __shared__ int cnt[256];
    __shared__ int pref[256];
    int b = blockIdx.x;
    int t = threadIdx.x;
    int bs = bucket_start[b], be = bucket_start[b + 1];
    cnt[t] = 0;
    __syncthreads();
    for (int i = bs + t; i < be; i += 256) atomicAdd(&cnt[gpacked[i] >> 16], 1);
    __syncthreads();
    int v = cnt[t];
    pref[t] = v;
    __syncthreads();
    for (int off = 1; off < 256; off <<= 1) {
        int u = 0;
        if (t >= off) u = pref[t - off];
        __syncthreads();
        if (t >= off) pref[t] += u;
        __syncthreads();
    }
    int excl = pref[t] - v;
    int node = b * 256 + t;
    if (node < N_NODES) row_start[node] = bs + excl;
    cnt[t] = excl;        // reuse as cursor
    __syncthreads();
    for (int i = bs + t; i < be; i += 256) {
        int p = gpacked[i];
        int pos = atomicAdd(&cnt[p >> 16], 1);
        edge_src[bs + pos] = p & 0xffff;
    }
}

// ---------- layer 1: gather(din=3) + MLP, one wave per node, bf16 out ----------
__global__ __launch_bounds__(256) void gin_layer3_kernel(
    const float* __restrict__ x, const int* __restrict__ row_start,
    const int* __restrict__ edge_src,
    const float* __restrict__ w1, const float* __restrict__ b1,
    const float* __restrict__ bn_g, const float* __restrict__ bn_b,
    const float* __restrict__ bn_m, const float* __restrict__ bn_v,
    const float* __restrict__ w2, const float* __restrict__ b2,
    __hip_bfloat16* __restrict__ hout) {
    __shared__ float s_w1[3 * H];
    __shared__ float s_w2[H * H];
    __shared__ float s_mid[4][H];
    __shared__ float s_scale[H], s_shift[H], s_b1[H], s_b2[H];

    int tid = threadIdx.x;
    for (int i = tid; i < 3 * H; i += 256) s_w1[i] = w1[i];
    for (int i = tid; i < H * H; i += 256) s_w2[i] = w2[i];
    if (tid < H) {
        float sc = rsqrtf(bn_v[tid] + BN_EPS) * bn_g[tid];
        s_scale[tid] = sc;
        s_shift[tid] = bn_b[tid] - bn_m[tid] * sc;
        s_b1[tid] = b1[tid];
        s_b2[tid] = b2[tid];
    }
    __syncthreads();

    int wave = tid >> 6;
    int j = tid & 63;
    int node = blockIdx.x * 4 + wave;

    int rs = row_start[node], re = row_start[node + 1];
    float a0 = 0.f, a1 = 0.f, a2 = 0.f;
    for (int t = rs + j; t < re; t += 64) {
        int s = edge_src[t];
        a0 += x[s * 3 + 0];
        a1 += x[s * 3 + 1];
        a2 += x[s * 3 + 2];
    }
#pragma unroll
    for (int off = 32; off > 0; off >>= 1) {
        a0 += __shfl_xor(a0, off);
        a1 += __shfl_xor(a1, off);
        a2 += __shfl_xor(a2, off);
    }
    float in0 = a0 + x[node * 3 + 0];
    float in1 = a1 + x[node * 3 + 1];
    float in2 = a2 + x[node * 3 + 2];

    float m = s_b1[j] + in0 * s_w1[0 * H + j] + in1 * s_w1[1 * H + j] + in2 * s_w1[2 * H + j];
    m = m * s_scale[j] + s_shift[j];
    m = fmaxf(m, 0.f);
    s_mid[wave][j] = m;
    __syncthreads();
    float o = s_b2[j];
#pragma unroll
    for (int k = 0; k < H; k++) o += s_mid[wave][k] * s_w2[k * H + j];
    o = fmaxf(o, 0.f);
    hout[(size_t)node * H + j] = __float2bfloat16(o);
}

// ---------- pure gather: xs[n] = h[n] + sum_{j->n} h[j], dwordx4 scheme ----------
// octet o = lane>>3 handles edge i+o; lane loads 16B = 8 features. One load
// instruction covers EIGHT edges. Cross-octet reduce via shfl_xor(8/16/32).
__global__ __launch_bounds__(512) void gather_kernel(
    const __hip_bfloat16* __restrict__ hin, const int* __restrict__ row_start,
    const int* __restrict__ edge_src, __hip_bfloat16* __restrict__ xs) {
    int tid = threadIdx.x;
    int wave = tid >> 6;
    int j = tid & 63;
    int o = j >> 3;    // 0..7: which edge of the group of 8
    int jo = j & 7;    // feature octet: features 8*jo .. 8*jo+7
    int node = blockIdx.x * 8 + wave;   // grid exactly covers N

    const char* hb = (const char*)hin;
    int rs = row_start[node], re = row_start[node + 1];
    float a0 = 0.f, a1 = 0.f, a2 = 0.f, a3 = 0.f, a4 = 0.f, a5 = 0.f, a6 = 0.f, a7 = 0.f;
    for (int base = rs; base < re; base += 64) {
        int idx = base + j;
        int sv = (idx < re) ? edge_src[idx] : 0;
        int cnt = min(64, re - base);
        int i = 0;
        for (; i + 8 <= cnt; i += 8) {
            int s = __shfl(sv, i + o);
            uint4 raw = *(const uint4*)(hb + (size_t)s * 128 + jo * 16);
            a0 += bflo(raw.x); a1 += bfhi(raw.x);
            a2 += bflo(raw.y); a3 += bfhi(raw.y);
            a4 += bflo(raw.z); a5 += bfhi(raw.z);
            a6 += bflo(raw.w); a7 += bfhi(raw.w);
        }
        if (i < cnt) {
            int r = cnt - i;
            int s = __shfl(sv, i + (o < r ? o : 0));
            uint4 raw = *(const uint4*)(hb + (size_t)s * 128 + jo * 16);
            if (o < r) {
                a0 += bflo(raw.x); a1 += bfhi(raw.x);
                a2 += bflo(raw.y); a3 += bfhi(raw.y);
                a4 += bflo(raw.z); a5 += bfhi(raw.z);
                a6 += bflo(raw.w); a7 += bfhi(raw.w);
            }
        }
    }
    a0 += __shfl_xor(a0, 8); a0 += __shfl_xor(a0, 16); a0 += __shfl_xor(a0, 32);
    a1 += __shfl_xor(a1, 8); a1 += __shfl_xor(a1, 16); a1 += __shfl_xor(a1, 32);
    a2 += __shfl_xor(a2, 8); a2 += __shfl_xor(a2, 16); a2 += __shfl_xor(a2, 32);
    a3 += __shfl_xor(a3, 8); a3 += __shfl_xor(a3, 16); a3 += __shfl_xor(a3, 32);
    a4 += __shfl_xor(a4, 8); a4 += __shfl_xor(a4, 16); a4 += __shfl_xor(a4, 32);
    a5 += __shfl_xor(a5, 8); a5 += __shfl_xor(a5, 16); a5 += __shfl_xor(a5, 32);
    a6 += __shfl_xor(a6, 8); a6 += __shfl_xor(a6, 16); a6 += __shfl_xor(a6, 32);
    a7 += __shfl_xor(a7, 8); a7 += __shfl_xor(a7, 16); a7 += __shfl_xor(a7, 32);
    if (o == 0) {
        uint4 raw = *(const uint4*)(hb + (size_t)node * 128 + jo * 16);
        a0 += bflo(raw.x); a1 += bfhi(raw.x);
        a2 += bflo(raw.y); a3 += bfhi(raw.y);
        a4 += bflo(raw.z); a5 += bfhi(raw.z);
        a6 += bflo(raw.w); a7 += bfhi(raw.w);
        uint4 ov;
        ov.x = bf16_rne(a0) | (bf16_rne(a1) << 16);
        ov.y = bf16_rne(a2) | (bf16_rne(a3) << 16);
        ov.z = bf16_rne(a4) | (bf16_rne(a5) << 16);
        ov.w = bf16_rne(a6) | (bf16_rne(a7) << 16);
        *(uint4*)((char*)xs + (size_t)node * 128 + jo * 16) = ov;
    }
}

// ---------- batched MFMA MLP: hout = relu(relu_bn(xs@w1+b1)@w2+b2) ----------
#define IOP 72
__global__ __launch_bounds__(256) void mlp_mfma_kernel(
    const __hip_bfloat16* __restrict__ xs,
    const float* __restrict__ w1, const float* __restrict__ b1,
    const float* __restrict__ bn_g, const float* __restrict__ bn_b,
    const float* __restrict__ bn_m, const float* __restrict__ bn_v,
    const float* __restrict__ w2, const float* __restrict__ b2,
    __hip_bfloat16* __restrict__ hout) {
    __shared__ unsigned short s_w1t[H * IOP];
    __shared__ unsigned short s_w2t[H * IOP];
    __shared__ unsigned short s_mid[4][16 * IOP];
    __shared__ unsigned short s_out[4][16 * IOP];

    int tid = threadIdx.x;
    for (int idx = tid; idx < H * H; idx += 256) {
        int k = idx >> 6, jj = idx & 63;
        s_w1t[jj * IOP + k] = (unsigned short)bf16_rne(w1[idx]);
        s_w2t[jj * IOP + k] = (unsigned short)bf16_rne(w2[idx]);
    }
    int lane = tid & 63, wave = tid >> 6;
    int quad = lane >> 4, l15 = lane & 15;
    float scl[4], sht[4], bb1[4], bb2[4];
#pragma unroll
    for (int jt = 0; jt < 4; jt++) {
        int j = jt * 16 + l15;
        float sc = rsqrtf(bn_v[j] + BN_EPS) * bn_g[j];
        scl[jt] = sc;
        sht[jt] = bn_b[j] - bn_m[j] * sc;
        bb1[jt] = b1[j];
        bb2[jt] = b2[j];
    }
    __syncthreads();

    int base = blockIdx.x * 64 + wave * 16;
    const unsigned short* xr = (const unsigned short*)xs;
    int am = min(base + l15, N_NODES - 1);
    short8 a0 = *(const short8*)(xr + (size_t)am * H + quad * 8);
    short8 a1 = *(const short8*)(xr + (size_t)am * H + quad * 8 + 32);

    unsigned short* mid = s_mid[wave];
    unsigned short* outw = s_out[wave];

#pragma unroll
    for (int jt = 0; jt < 4; jt++) {
        short8 b0 = *(const short8*)&s_w1t[(jt * 16 + l15) * IOP + quad * 8];
        short8 bv = *(const short8*)&s_w1t[(jt * 16 + l15) * IOP + quad * 8 + 32];
        floatx4 c = {0.f, 0.f, 0.f, 0.f};
        c = __builtin_amdgcn_mfma_f32_16x16x32_bf16(a0, b0, c, 0, 0, 0);
        c = __builtin_amdgcn_mfma_f32_16x16x32_bf16(a1, bv, c, 0, 0, 0);
#pragma unroll
        for (int r = 0; r < 4; r++) {
            float v = (c[r] + bb1[jt]) * scl[jt] + sht[jt];
            v = fmaxf(v, 0.f);
            mid[(quad * 4 + r) * IOP + jt * 16 + l15] = (unsigned short)bf16_rne(v);
        }
    }
    __syncthreads();

    short8 m0 = *(const short8*)&mid[l15 * IOP + quad * 8];
    short8 m1 = *(const short8*)&mid[l15 * IOP + quad * 8 + 32];
#pragma unroll
    for (int jt = 0; jt < 4; jt++) {
        short8 b0 = *(const short8*)&s_w2t[(jt * 16 + l15) * IOP + quad * 8];
        short8 bv = *(const short8*)&s_w2t[(jt * 16 + l15) * IOP + quad * 8 + 32];
        floatx4 c = {0.f, 0.f, 0.f, 0.f};
        c = __builtin_amdgcn_mfma_f32_16x16x32_bf16(m0, b0, c, 0, 0, 0);
        c = __builtin_amdgcn_mfma_f32_16x16x32_bf16(m1, bv, c, 0, 0, 0);
#pragma unroll
        for (int r = 0; r < 4; r++) {
            float v = fmaxf(c[r] + bb2[jt], 0.f);
            outw[(quad * 4 + r) * IOP + jt * 16 + l15] = (unsigned short)bf16_rne(v);
        }
    }
    __syncthreads();

    unsigned short* ho = (unsigned short*)hout;
#pragma unroll
    for (int cc = 0; cc < 2; cc++) {
        int r = cc * 8 + (lane >> 3);
        int node = base + r;
        if (node < N_NODES) {
            short8 v = *(const short8*)&outw[r * IOP + (lane & 7) * 8];
            *(short8*)(ho + (size_t)node * H + (lane & 7) * 8) = v;
        }
    }
}

// ---------- pool (batch sorted -> range per graph) + head ----------
__global__ __launch_bounds__(192) void pool_head_kernel(
    const __hip_bfloat16* __restrict__ h1, const __hip_bfloat16* __restrict__ h2,
    const __hip_bfloat16* __restrict__ h3, const int* __restrict__ batch,
    const float* __restrict__ lin1_w, const float* __restrict__ lin1_b,
    const float* __restrict__ lin2_w, const float* __restrict__ lin2_b,
    float* __restrict__ out) {
    __shared__ float s_row[3 * H];
    __shared__ float s_mid[3 * H];
    __shared__ float s_z[C_CLS];
    __shared__ int s_se[2];

    int g = blockIdx.x;
    int j = threadIdx.x;
    if (j < 2) {
        int target = g + j;
        int lo = 0, hi = N_NODES;
        while (lo < hi) {
            int mid = (lo + hi) >> 1;
            if (batch[mid] < target) lo = mid + 1; else hi = mid;
        }
        s_se[j] = lo;
    }
    __syncthreads();
    int ns = s_se[0], ne = s_se[1];

    int which = j >> 6;
    int f = j & 63;
    const __hip_bfloat16* h = (which == 0) ? h1 : ((which == 1) ? h2 : h3);
    float p0 = 0.f, p1 = 0.f, p2 = 0.f, p3 = 0.f;
    int n = ns;
    for (; n + 3 < ne; n += 4) {
        p0 += __bfloat162float(h[(size_t)n * H + f]);
        p1 += __bfloat162float(h[(size_t)(n + 1) * H + f]);
        p2 += __bfloat162float(h[(size_t)(n + 2) * H + f]);
        p3 += __bfloat162float(h[(size_t)(n + 3) * H + f]);
    }
    for (; n < ne; n++) p0 += __bfloat162float(h[(size_t)n * H + f]);
    s_row[j] = (p0 + p1) + (p2 + p3);
    __syncthreads();

    float acc = lin1_b[j];
    for (int k = 0; k < 3 * H; k++) acc += s_row[k] * lin1_w[k * (3 * H) + j];
    s_mid[j] = fmaxf(acc, 0.f);
    __syncthreads();

    if (j < C_CLS) {
        float z = lin2_b[j];
        for (int k = 0; k < 3 * H; k++) z += s_mid[k] * lin2_w[k * C_CLS + j];
        s_z[j] = z;
    }
    __syncthreads();
    if (j < C_CLS) {
        float z0 = s_z[0], z1 = s_z[1];
        float mx = fmaxf(z0, z1);
        float lse = mx + logf(expf(z0 - mx) + expf(z1 - mx));
        out[g * C_CLS + j] = s_z[j];
        out[G_GRAPHS * C_CLS + g * C_CLS + j] = s_z[j] - lse;
    }
}

extern "C" void kernel_launch(void* const* d_in, const int* in_sizes, int n_in,
                              void* d_out, int out_size, void* d_ws, size_t ws_size,
                              hipStream_t stream) {
    const float* x = (const float*)d_in[0];
    const float* cw1[3], *cb1[3], *cg[3], *cbb[3], *cm[3], *cv[3], *cw2[3], *cb2[3];
    for (int l = 0; l < 3; l++) {
        int b = 1 + 8 * l;
        cw1[l] = (const float*)d_in[b + 0];
        cb1[l] = (const float*)d_in[b + 1];
        cg[l]  = (const float*)d_in[b + 2];
        cbb[l] = (const float*)d_in[b + 3];
        cm[l]  = (const float*)d_in[b + 4];
        cv[l]  = (const float*)d_in[b + 5];
        cw2[l] = (const float*)d_in[b + 6];
        cb2[l] = (const float*)d_in[b + 7];
    }
    const float* lin1_w = (const float*)d_in[25];
    const float* lin1_b = (const float*)d_in[26];
    const float* lin2_w = (const float*)d_in[27];
    const float* lin2_b = (const float*)d_in[28];
    const int* edge_index = (const int*)d_in[29];
    const int* batch = (const int*)d_in[30];
    const int* src = edge_index;
    const int* dst = edge_index + N_EDGES;
    float* out = (float*)d_out;

    // workspace layout
    int* edge_src = (int*)d_ws;                     // E
    int* gpacked = edge_src + N_EDGES;              // E
    int* gbh = gpacked + N_EDGES;                   // NBUCK
    int* bucket_start = gbh + NBUCK;                // NBUCK+1
    int* cursor = bucket_start + NBUCK + 1;         // NBUCK
    int* row_start = cursor + NBUCK;                // N+2
    uintptr_t hp = (uintptr_t)(row_start + N_NODES + 2);
    hp = (hp + 127) & ~(uintptr_t)127;
    __hip_bfloat16* h1 = (__hip_bfloat16*)hp;       // N*H each
    __hip_bfloat16* h2 = h1 + (size_t)N_NODES * H;
    __hip_bfloat16* h3 = h2 + (size_t)N_NODES * H;
    __hip_bfloat16* xs = h3 + (size_t)N_NODES * H;

    // ---- build CSR via 2-digit radix (LDS atomics, ~150k global atomics) ----
    hipMemsetAsync(gbh, 0, NBUCK * sizeof(int), stream);
    bhist_kernel<<<CSR_BLOCKS, 256, 0, stream>>>(dst, gbh);
    bscan_kernel<<<1, 256, 0, stream>>>(gbh, bucket_start, cursor, row_start);
    bscatter_kernel<<<CSR_BLOCKS, 256, 0, stream>>>(src, dst, cursor, gpacked);
    bcsr_kernel<<<NBUCK, 256, 0, stream>>>(gpacked, bucket_start, row_start, edge_src);

    const int mlp_grid = (N_NODES + 63) / 64;   // 782

    // ---- layer 1 ----
    gin_layer3_kernel<<<N_NODES / 4, 256, 0, stream>>>(x, row_start, edge_src,
        cw1[0], cb1[0], cg[0], cbb[0], cm[0], cv[0], cw2[0], cb2[0], h1);
    // ---- layer 2 ----
    gather_kernel<<<N_NODES / 8, 512, 0, stream>>>(h1, row_start, edge_src, xs);
    mlp_mfma_kernel<<<mlp_grid, 256, 0, stream>>>(xs,
        cw1[1], cb1[1], cg[1], cbb[1], cm[1], cv[1], cw2[1], cb2[1], h2);
    // ---- layer 3 ----
    gather_kernel<<<N_NODES / 8, 512, 0, stream>>>(h2, row_start, edge_src, xs);
    mlp_mfma_kernel<<<mlp_grid, 256, 0, stream>>>(xs,
        cw1[2], cb1[2], cg[2], cbb[2], cm[2], cv[2], cw2[2], cb2[2], h3);
    // ---- pool + head ----
    pool_head_kernel<<<G_GRAPHS, 3 * H, 0, stream>>>(h1, h2, h3, batch,
        lin1_w, lin1_b, lin2_w, lin2_b, out);
}

// Round 9
// 310.190 us; speedup vs baseline: 1.6429x; 1.0635x over previous
//
#include <hip/hip_runtime.h>
#include <hip/hip_bf16.h>
#include <math.h>

#define N_NODES 50000
#define N_EDGES 1600000
#define H 64
#define G_GRAPHS 512
#define C_CLS 2
#define BN_EPS 1e-5f
#define NBUCK 196           // buckets of 256 nodes: dst>>8 in [0,196)
#define E4 (N_EDGES / 4)    // 400000
#define CSR_BLOCKS ((E4 + 511) / 512)   // 782, each handles 2048 edges

typedef __attribute__((ext_vector_type(8))) short short8;
typedef __attribute__((ext_vector_type(4))) float floatx4;

__device__ __forceinline__ float bflo(unsigned int u) { return __uint_as_float(u << 16); }
__device__ __forceinline__ float bfhi(unsigned int u) { return __uint_as_float(u & 0xffff0000u); }
__device__ __forceinline__ unsigned int bf16_rne(float f) {
    unsigned int u = __float_as_uint(f);
    u += 0x7fffu + ((u >> 16) & 1u);
    return u >> 16;
}

// ---------- CSR pass 1: global bucket histogram (LDS-privatized) ----------
__global__ __launch_bounds__(256) void bhist_kernel(const int* __restrict__ dst,
                                                    int* __restrict__ gbh) {
    __shared__ int bh[NBUCK];
    int t = threadIdx.x;
    if (t < NBUCK) bh[t] = 0;
    __syncthreads();
    int base = blockIdx.x * 512;
#pragma unroll
    for (int p = 0; p < 2; p++) {
        int i = base + p * 256 + t;
        if (i < E4) {
            int4 d = ((const int4*)dst)[i];
            atomicAdd(&bh[d.x >> 8], 1);
            atomicAdd(&bh[d.y >> 8], 1);
            atomicAdd(&bh[d.z >> 8], 1);
            atomicAdd(&bh[d.w >> 8], 1);
        }
    }
    __syncthreads();
    if (t < NBUCK && bh[t]) atomicAdd(&gbh[t], bh[t]);
}

// ---------- CSR pass 2: exclusive scan of 196 bucket counts ----------
__global__ __launch_bounds__(256) void bscan_kernel(const int* __restrict__ gbh,
                                                    int* __restrict__ bucket_start,
                                                    int* __restrict__ cursor,
                                                    int* __restrict__ row_start) {
    __shared__ int s[256];
    int t = threadIdx.x;
    int v = (t < NBUCK) ? gbh[t] : 0;
    s[t] = v;
    __syncthreads();
    for (int off = 1; off < 256; off <<= 1) {
        int u = 0;
        if (t >= off) u = s[t - off];
        __syncthreads();
        if (t >= off) s[t] += u;
        __syncthreads();
    }
    int excl = s[t] - v;
    if (t < NBUCK) { bucket_start[t] = excl; cursor[t] = excl; }
    if (t == 0) { bucket_start[NBUCK] = N_EDGES; row_start[N_NODES] = N_EDGES; }
}

// ---------- CSR pass 3: scatter edges into buckets (rank via LDS atomics) ----------
__global__ __launch_bounds__(256) void bscatter_kernel(const int* __restrict__ src,
                                                       const int* __restrict__ dst,
                                                       int* __restrict__ cursor,
                                                       int* __restrict__ gpacked) {
    __shared__ int bh[NBUCK];
    int t = threadIdx.x;
    if (t < NBUCK) bh[t] = 0;
    __syncthreads();
    int base = blockIdx.x * 512;

    int pkA[4], bkA[4], lrA[4]; bool vA = false;
    int pkB[4], bkB[4], lrB[4]; bool vB = false;
    {
        int i = base + t;
        if (i < E4) {
            vA = true;
            int4 s4 = ((const int4*)src)[i];
            int4 d4 = ((const int4*)dst)[i];
            bkA[0] = d4.x >> 8; pkA[0] = ((d4.x & 255) << 16) | s4.x; lrA[0] = atomicAdd(&bh[bkA[0]], 1);
            bkA[1] = d4.y >> 8; pkA[1] = ((d4.y & 255) << 16) | s4.y; lrA[1] = atomicAdd(&bh[bkA[1]], 1);
            bkA[2] = d4.z >> 8; pkA[2] = ((d4.z & 255) << 16) | s4.z; lrA[2] = atomicAdd(&bh[bkA[2]], 1);
            bkA[3] = d4.w >> 8; pkA[3] = ((d4.w & 255) << 16) | s4.w; lrA[3] = atomicAdd(&bh[bkA[3]], 1);
        }
    }
    {
        int i = base + 256 + t;
        if (i < E4) {
            vB = true;
            int4 s4 = ((const int4*)src)[i];
            int4 d4 = ((const int4*)dst)[i];
            bkB[0] = d4.x >> 8; pkB[0] = ((d4.x & 255) << 16) | s4.x; lrB[0] = atomicAdd(&bh[bkB[0]], 1);
            bkB[1] = d4.y >> 8; pkB[1] = ((d4.y & 255) << 16) | s4.y; lrB[1] = atomicAdd(&bh[bkB[1]], 1);
            bkB[2] = d4.z >> 8; pkB[2] = ((d4.z & 255) << 16) | s4.z; lrB[2] = atomicAdd(&bh[bkB[2]], 1);
            bkB[3] = d4.w >> 8; pkB[3] = ((d4.w & 255) << 16) | s4.w; lrB[3] = atomicAdd(&bh[bkB[3]], 1);
        }
    }
    __syncthreads();
    if (t < NBUCK) {
        int c = bh[t];
        bh[t] = c ? atomicAdd(&cursor[t], c) : 0;   // per-(block,bucket) base
    }
    __syncthreads();
    if (vA) {
#pragma unroll
        for (int q = 0; q < 4; q++) gpacked[bh[bkA[q]] + lrA[q]] = pkA[q];
    }
    if (vB) {
#pragma unroll
        for (int q = 0; q < 4; q++) gpacked[bh[bkB[q]] + lrB[q]] = pkB[q];
    }
}

// ---------- CSR pass 4: per-bucket local CSR (256 nodes/bucket) ----------
__global__ __launch_bounds__(256) void bcsr_kernel(const int* __restrict__ gpacked,
                                                   const int* __restrict__ bucket_start,
                                                   int* __restrict__ row_start,
                                                   int* __restrict__ edge_src) {
    __shared__ int cnt[256];
    __shared__ int pref[256];
    int b = blockIdx.x;
    int t = threadIdx.x;
    int bs = bucket_start[b], be = bucket_start[b + 1];
    cnt[t] = 0;
    __syncthreads();
    for (int i = bs + t; i < be; i += 256) atomicAdd(&cnt[gpacked[i] >> 16], 1);
    __syncthreads();
    int v = cnt[t];
    pref[t] = v;
    __syncthreads();
    for (int off = 1; off < 256; off <<= 1) {
        int u = 0;
        if (t >= off) u = pref[t - off];
        __syncthreads();
        if (t >= off) pref[t] += u;
        __syncthreads();
    }
    int excl = pref[t] - v;
    int node = b * 256 + t;
    if (node < N_NODES) row_start[node] = bs + excl;
    cnt[t] = excl;        // reuse as cursor
    __syncthreads();
    for (int i = bs + t; i < be; i += 256) {
        int p = gpacked[i];
        int pos = atomicAdd(&cnt[p >> 16], 1);
        edge_src[bs + pos] = p & 0xffff;
    }
}

// ---------- layer 1a: gather(din=3) + first linear + BN + relu, no LDS ----------
__global__ __launch_bounds__(512) void gather3_mid_kernel(
    const float* __restrict__ x, const int* __restrict__ row_start,
    const int* __restrict__ edge_src,
    const float* __restrict__ w1, const float* __restrict__ b1,
    const float* __restrict__ bn_g, const float* __restrict__ bn_b,
    const float* __restrict__ bn_m, const float* __restrict__ bn_v,
    __hip_bfloat16* __restrict__ mid) {
    int tid = threadIdx.x;
    int wave = tid >> 6;
    int j = tid & 63;
    int node = blockIdx.x * 8 + wave;   // grid exactly covers N

    int rs = row_start[node], re = row_start[node + 1];
    float a0 = 0.f, a1 = 0.f, a2 = 0.f;
    for (int t = rs + j; t < re; t += 64) {
        int s = edge_src[t];
        a0 += x[s * 3 + 0];
        a1 += x[s * 3 + 1];
        a2 += x[s * 3 + 2];
    }
#pragma unroll
    for (int off = 32; off > 0; off >>= 1) {
        a0 += __shfl_xor(a0, off);
        a1 += __shfl_xor(a1, off);
        a2 += __shfl_xor(a2, off);
    }
    float in0 = a0 + x[node * 3 + 0];
    float in1 = a1 + x[node * 3 + 1];
    float in2 = a2 + x[node * 3 + 2];

    float sc = rsqrtf(bn_v[j] + BN_EPS) * bn_g[j];
    float sh = bn_b[j] - bn_m[j] * sc;
    float m = b1[j] + in0 * w1[j] + in1 * w1[H + j] + in2 * w1[2 * H + j];
    m = fmaxf(m * sc + sh, 0.f);
    ((unsigned short*)mid)[(size_t)node * H + j] = (unsigned short)bf16_rne(m);
}

// ---------- layer 1b: h1 = relu(mid@w2 + b2) via MFMA ----------
#define IOP 72
__global__ __launch_bounds__(256) void matmul2_mfma_kernel(
    const __hip_bfloat16* __restrict__ xin,
    const float* __restrict__ w2, const float* __restrict__ b2,
    __hip_bfloat16* __restrict__ hout) {
    __shared__ unsigned short s_w2t[H * IOP];
    __shared__ unsigned short s_out[4][16 * IOP];

    int tid = threadIdx.x;
    for (int idx = tid; idx < H * H; idx += 256) {
        int k = idx >> 6, jj = idx & 63;
        s_w2t[jj * IOP + k] = (unsigned short)bf16_rne(w2[idx]);
    }
    int lane = tid & 63, wave = tid >> 6;
    int quad = lane >> 4, l15 = lane & 15;
    float bb2[4];
#pragma unroll
    for (int jt = 0; jt < 4; jt++) bb2[jt] = b2[jt * 16 + l15];
    __syncthreads();

    int base = blockIdx.x * 64 + wave * 16;
    const unsigned short* xr = (const unsigned short*)xin;
    int am = min(base + l15, N_NODES - 1);
    short8 a0 = *(const short8*)(xr + (size_t)am * H + quad * 8);
    short8 a1 = *(const short8*)(xr + (size_t)am * H + quad * 8 + 32);

    unsigned short* outw = s_out[wave];
#pragma unroll
    for (int jt = 0; jt < 4; jt++) {
        short8 b0 = *(const short8*)&s_w2t[(jt * 16 + l15) * IOP + quad * 8];
        short8 bv = *(const short8*)&s_w2t[(jt * 16 + l15) * IOP + quad * 8 + 32];
        floatx4 c = {0.f, 0.f, 0.f, 0.f};
        c = __builtin_amdgcn_mfma_f32_16x16x32_bf16(a0, b0, c, 0, 0, 0);
        c = __builtin_amdgcn_mfma_f32_16x16x32_bf16(a1, bv, c, 0, 0, 0);
#pragma unroll
        for (int r = 0; r < 4; r++) {
            float v = fmaxf(c[r] + bb2[jt], 0.f);
            outw[(quad * 4 + r) * IOP + jt * 16 + l15] = (unsigned short)bf16_rne(v);
        }
    }
    __syncthreads();

    unsigned short* ho = (unsigned short*)hout;
#pragma unroll
    for (int cc = 0; cc < 2; cc++) {
        int r = cc * 8 + (lane >> 3);
        int node = base + r;
        if (node < N_NODES) {
            short8 v = *(const short8*)&outw[r * IOP + (lane & 7) * 8];
            *(short8*)(ho + (size_t)node * H + (lane & 7) * 8) = v;
        }
    }
}

// ---------- pure gather: xs[n] = h[n] + sum_{j->n} h[j], dwordx4 scheme ----------
__global__ __launch_bounds__(512) void gather_kernel(
    const __hip_bfloat16* __restrict__ hin, const int* __restrict__ row_start,
    const int* __restrict__ edge_src, __hip_bfloat16* __restrict__ xs) {
    int tid = threadIdx.x;
    int wave = tid >> 6;
    int j = tid & 63;
    int o = j >> 3;    // 0..7: which edge of the group of 8
    int jo = j & 7;    // feature octet: features 8*jo .. 8*jo+7
    int node = blockIdx.x * 8 + wave;   // grid exactly covers N

    const char* hb = (const char*)hin;
    int rs = row_start[node], re = row_start[node + 1];
    float a0 = 0.f, a1 = 0.f, a2 = 0.f, a3 = 0.f, a4 = 0.f, a5 = 0.f, a6 = 0.f, a7 = 0.f;
    for (int base = rs; base < re; base += 64) {
        int idx = base + j;
        int sv = (idx < re) ? edge_src[idx] : 0;
        int cnt = min(64, re - base);
        int i = 0;
        for (; i + 8 <= cnt; i += 8) {
            int s = __shfl(sv, i + o);
            uint4 raw = *(const uint4*)(hb + (size_t)s * 128 + jo * 16);
            a0 += bflo(raw.x); a1 += bfhi(raw.x);
            a2 += bflo(raw.y); a3 += bfhi(raw.y);
            a4 += bflo(raw.z); a5 += bfhi(raw.z);
            a6 += bflo(raw.w); a7 += bfhi(raw.w);
        }
        if (i < cnt) {
            int r = cnt - i;
            int s = __shfl(sv, i + (o < r ? o : 0));
            uint4 raw = *(const uint4*)(hb + (size_t)s * 128 + jo * 16);
            if (o < r) {
                a0 += bflo(raw.x); a1 += bfhi(raw.x);
                a2 += bflo(raw.y); a3 += bfhi(raw.y);
                a4 += bflo(raw.z); a5 += bfhi(raw.z);
                a6 += bflo(raw.w); a7 += bfhi(raw.w);
            }
        }
    }
    a0 += __shfl_xor(a0, 8); a0 += __shfl_xor(a0, 16); a0 += __shfl_xor(a0, 32);
    a1 += __shfl_xor(a1, 8); a1 += __shfl_xor(a1, 16); a1 += __shfl_xor(a1, 32);
    a2 += __shfl_xor(a2, 8); a2 += __shfl_xor(a2, 16); a2 += __shfl_xor(a2, 32);
    a3 += __shfl_xor(a3, 8); a3 += __shfl_xor(a3, 16); a3 += __shfl_xor(a3, 32);
    a4 += __shfl_xor(a4, 8); a4 += __shfl_xor(a4, 16); a4 += __shfl_xor(a4, 32);
    a5 += __shfl_xor(a5, 8); a5 += __shfl_xor(a5, 16); a5 += __shfl_xor(a5, 32);
    a6 += __shfl_xor(a6, 8); a6 += __shfl_xor(a6, 16); a6 += __shfl_xor(a6, 32);
    a7 += __shfl_xor(a7, 8); a7 += __shfl_xor(a7, 16); a7 += __shfl_xor(a7, 32);
    if (o == 0) {
        uint4 raw = *(const uint4*)(hb + (size_t)node * 128 + jo * 16);
        a0 += bflo(raw.x); a1 += bfhi(raw.x);
        a2 += bflo(raw.y); a3 += bfhi(raw.y);
        a4 += bflo(raw.z); a5 += bfhi(raw.z);
        a6 += bflo(raw.w); a7 += bfhi(raw.w);
        uint4 ov;
        ov.x = bf16_rne(a0) | (bf16_rne(a1) << 16);
        ov.y = bf16_rne(a2) | (bf16_rne(a3) << 16);
        ov.z = bf16_rne(a4) | (bf16_rne(a5) << 16);
        ov.w = bf16_rne(a6) | (bf16_rne(a7) << 16);
        *(uint4*)((char*)xs + (size_t)node * 128 + jo * 16) = ov;
    }
}

// ---------- batched MFMA MLP: hout = relu(relu_bn(xs@w1+b1)@w2+b2) ----------
__global__ __launch_bounds__(256) void mlp_mfma_kernel(
    const __hip_bfloat16* __restrict__ xs,
    const float* __restrict__ w1, const float* __restrict__ b1,
    const float* __restrict__ bn_g, const float* __restrict__ bn_b,
    const float* __restrict__ bn_m, const float* __restrict__ bn_v,
    const float* __restrict__ w2, const float* __restrict__ b2,
    __hip_bfloat16* __restrict__ hout) {
    __shared__ unsigned short s_w1t[H * IOP];
    __shared__ unsigned short s_w2t[H * IOP];
    __shared__ unsigned short s_mid[4][16 * IOP];
    __shared__ unsigned short s_out[4][16 * IOP];

    int tid = threadIdx.x;
    for (int idx = tid; idx < H * H; idx += 256) {
        int k = idx >> 6, jj = idx & 63;
        s_w1t[jj * IOP + k] = (unsigned short)bf16_rne(w1[idx]);
        s_w2t[jj * IOP + k] = (unsigned short)bf16_rne(w2[idx]);
    }
    int lane = tid & 63, wave = tid >> 6;
    int quad = lane >> 4, l15 = lane & 15;
    float scl[4], sht[4], bb1[4], bb2[4];
#pragma unroll
    for (int jt = 0; jt < 4; jt++) {
        int j = jt * 16 + l15;
        float sc = rsqrtf(bn_v[j] + BN_EPS) * bn_g[j];
        scl[jt] = sc;
        sht[jt] = bn_b[j] - bn_m[j] * sc;
        bb1[jt] = b1[j];
        bb2[jt] = b2[j];
    }
    __syncthreads();

    int base = blockIdx.x * 64 + wave * 16;
    const unsigned short* xr = (const unsigned short*)xs;
    int am = min(base + l15, N_NODES - 1);
    short8 a0 = *(const short8*)(xr + (size_t)am * H + quad * 8);
    short8 a1 = *(const short8*)(xr + (size_t)am * H + quad * 8 + 32);

    unsigned short* mid = s_mid[wave];
    unsigned short* outw = s_out[wave];

#pragma unroll
    for (int jt = 0; jt < 4; jt++) {
        short8 b0 = *(const short8*)&s_w1t[(jt * 16 + l15) * IOP + quad * 8];
        short8 bv = *(const short8*)&s_w1t[(jt * 16 + l15) * IOP + quad * 8 + 32];
        floatx4 c = {0.f, 0.f, 0.f, 0.f};
        c = __builtin_amdgcn_mfma_f32_16x16x32_bf16(a0, b0, c, 0, 0, 0);
        c = __builtin_amdgcn_mfma_f32_16x16x32_bf16(a1, bv, c, 0, 0, 0);
#pragma unroll
        for (int r = 0; r < 4; r++) {
            float v = (c[r] + bb1[jt]) * scl[jt] + sht[jt];
            v = fmaxf(v, 0.f);
            mid[(quad * 4 + r) * IOP + jt * 16 + l15] = (unsigned short)bf16_rne(v);
        }
    }
    __syncthreads();

    short8 m0 = *(const short8*)&mid[l15 * IOP + quad * 8];
    short8 m1 = *(const short8*)&mid[l15 * IOP + quad * 8 + 32];
#pragma unroll
    for (int jt = 0; jt < 4; jt++) {
        short8 b0 = *(const short8*)&s_w2t[(jt * 16 + l15) * IOP + quad * 8];
        short8 bv = *(const short8*)&s_w2t[(jt * 16 + l15) * IOP + quad * 8 + 32];
        floatx4 c = {0.f, 0.f, 0.f, 0.f};
        c = __builtin_amdgcn_mfma_f32_16x16x32_bf16(m0, b0, c, 0, 0, 0);
        c = __builtin_amdgcn_mfma_f32_16x16x32_bf16(m1, bv, c, 0, 0, 0);
#pragma unroll
        for (int r = 0; r < 4; r++) {
            float v = fmaxf(c[r] + bb2[jt], 0.f);
            outw[(quad * 4 + r) * IOP + jt * 16 + l15] = (unsigned short)bf16_rne(v);
        }
    }
    __syncthreads();

    unsigned short* ho = (unsigned short*)hout;
#pragma unroll
    for (int cc = 0; cc < 2; cc++) {
        int r = cc * 8 + (lane >> 3);
        int node = base + r;
        if (node < N_NODES) {
            short8 v = *(const short8*)&outw[r * IOP + (lane & 7) * 8];
            *(short8*)(ho + (size_t)node * H + (lane & 7) * 8) = v;
        }
    }
}

// ---------- pool (batch sorted -> range per graph) + head ----------
__global__ __launch_bounds__(192) void pool_head_kernel(
    const __hip_bfloat16* __restrict__ h1, const __hip_bfloat16* __restrict__ h2,
    const __hip_bfloat16* __restrict__ h3, const int* __restrict__ batch,
    const float* __restrict__ lin1_w, const float* __restrict__ lin1_b,
    const float* __restrict__ lin2_w, const float* __restrict__ lin2_b,
    float* __restrict__ out) {
    __shared__ float s_row[3 * H];
    __shared__ float s_mid[3 * H];
    __shared__ float s_z[C_CLS];
    __shared__ int s_se[2];

    int g = blockIdx.x;
    int j = threadIdx.x;
    if (j < 2) {
        int target = g + j;
        int lo = 0, hi = N_NODES;
        while (lo < hi) {
            int mid = (lo + hi) >> 1;
            if (batch[mid] < target) lo = mid + 1; else hi = mid;
        }
        s_se[j] = lo;
    }
    __syncthreads();
    int ns = s_se[0], ne = s_se[1];

    int which = j >> 6;
    int f = j & 63;
    const __hip_bfloat16* h = (which == 0) ? h1 : ((which == 1) ? h2 : h3);
    float p0 = 0.f, p1 = 0.f, p2 = 0.f, p3 = 0.f;
    int n = ns;
    for (; n + 3 < ne; n += 4) {
        p0 += __bfloat162float(h[(size_t)n * H + f]);
        p1 += __bfloat162float(h[(size_t)(n + 1) * H + f]);
        p2 += __bfloat162float(h[(size_t)(n + 2) * H + f]);
        p3 += __bfloat162float(h[(size_t)(n + 3) * H + f]);
    }
    for (; n < ne; n++) p0 += __bfloat162float(h[(size_t)n * H + f]);
    s_row[j] = (p0 + p1) + (p2 + p3);
    __syncthreads();

    float acc = lin1_b[j];
    for (int k = 0; k < 3 * H; k++) acc += s_row[k] * lin1_w[k * (3 * H) + j];
    s_mid[j] = fmaxf(acc, 0.f);
    __syncthreads();

    if (j < C_CLS) {
        float z = lin2_b[j];
        for (int k = 0; k < 3 * H; k++) z += s_mid[k] * lin2_w[k * C_CLS + j];
        s_z[j] = z;
    }
    __syncthreads();
    if (j < C_CLS) {
        float z0 = s_z[0], z1 = s_z[1];
        float mx = fmaxf(z0, z1);
        float lse = mx + logf(expf(z0 - mx) + expf(z1 - mx));
        out[g * C_CLS + j] = s_z[j];
        out[G_GRAPHS * C_CLS + g * C_CLS + j] = s_z[j] - lse;
    }
}

extern "C" void kernel_launch(void* const* d_in, const int* in_sizes, int n_in,
                              void* d_out, int out_size, void* d_ws, size_t ws_size,
                              hipStream_t stream) {
    const float* x = (const float*)d_in[0];
    const float* cw1[3], *cb1[3], *cg[3], *cbb[3], *cm[3], *cv[3], *cw2[3], *cb2[3];
    for (int l = 0; l < 3; l++) {
        int b = 1 + 8 * l;
        cw1[l] = (const float*)d_in[b + 0];
        cb1[l] = (const float*)d_in[b + 1];
        cg[l]  = (const float*)d_in[b + 2];
        cbb[l] = (const float*)d_in[b + 3];
        cm[l]  = (const float*)d_in[b + 4];
        cv[l]  = (const float*)d_in[b + 5];
        cw2[l] = (const float*)d_in[b + 6];
        cb2[l] = (const float*)d_in[b + 7];
    }
    const float* lin1_w = (const float*)d_in[25];
    const float* lin1_b = (const float*)d_in[26];
    const float* lin2_w = (const float*)d_in[27];
    const float* lin2_b = (const float*)d_in[28];
    const int* edge_index = (const int*)d_in[29];
    const int* batch = (const int*)d_in[30];
    const int* src = edge_index;
    const int* dst = edge_index + N_EDGES;
    float* out = (float*)d_out;

    // workspace layout
    int* edge_src = (int*)d_ws;                     // E
    int* gpacked = edge_src + N_EDGES;              // E
    int* gbh = gpacked + N_EDGES;                   // NBUCK
    int* bucket_start = gbh + NBUCK;                // NBUCK+1
    int* cursor = bucket_start + NBUCK + 1;         // NBUCK
    int* row_start = cursor + NBUCK;                // N+2
    uintptr_t hp = (uintptr_t)(row_start + N_NODES + 2);
    hp = (hp + 127) & ~(uintptr_t)127;
    __hip_bfloat16* h1 = (__hip_bfloat16*)hp;       // N*H each
    __hip_bfloat16* h2 = h1 + (size_t)N_NODES * H;
    __hip_bfloat16* h3 = h2 + (size_t)N_NODES * H;
    __hip_bfloat16* xs = h3 + (size_t)N_NODES * H;

    // ---- build CSR via 2-digit radix (LDS atomics, ~150k global atomics) ----
    hipMemsetAsync(gbh, 0, NBUCK * sizeof(int), stream);
    bhist_kernel<<<CSR_BLOCKS, 256, 0, stream>>>(dst, gbh);
    bscan_kernel<<<1, 256, 0, stream>>>(gbh, bucket_start, cursor, row_start);
    bscatter_kernel<<<CSR_BLOCKS, 256, 0, stream>>>(src, dst, cursor, gpacked);
    bcsr_kernel<<<NBUCK, 256, 0, stream>>>(gpacked, bucket_start, row_start, edge_src);

    const int mlp_grid = (N_NODES + 63) / 64;   // 782

    // ---- layer 1 ----
    gather3_mid_kernel<<<N_NODES / 8, 512, 0, stream>>>(x, row_start, edge_src,
        cw1[0], cb1[0], cg[0], cbb[0], cm[0], cv[0], xs);
    matmul2_mfma_kernel<<<mlp_grid, 256, 0, stream>>>(xs, cw2[0], cb2[0], h1);
    // ---- layer 2 ----
    gather_kernel<<<N_NODES / 8, 512, 0, stream>>>(h1, row_start, edge_src, xs);
    mlp_mfma_kernel<<<mlp_grid, 256, 0, stream>>>(xs,
        cw1[1], cb1[1], cg[1], cbb[1], cm[1], cv[1], cw2[1], cb2[1], h2);
    // ---- layer 3 ----
    gather_kernel<<<N_NODES / 8, 512, 0, stream>>>(h2, row_start, edge_src, xs);
    mlp_mfma_kernel<<<mlp_grid, 256, 0, stream>>>(xs,
        cw1[2], cb1[2], cg[2], cbb[2], cm[2], cv[2], cw2[2], cb2[2], h3);
    // ---- pool + head ----
    pool_head_kernel<<<G_GRAPHS, 3 * H, 0, stream>>>(h1, h2, h3, batch,
        lin1_w, lin1_b, lin2_w, lin2_b, out);
}